// Round 1
// baseline (704.151 us; speedup 1.0000x reference)
//
#include <hip/hip_runtime.h>
#include <cstdint>
#include <cstddef>

#define D_MODELX 1024
#define NUM_HEADX 16
#define D_KX 64
#define BBX 2
#define SSX 2048
#define M_TOK 4096   // B*S

typedef __attribute__((ext_vector_type(8))) short short8;
typedef __attribute__((ext_vector_type(4))) short short4v;
typedef __attribute__((ext_vector_type(4))) float float4v;

__device__ __forceinline__ short f2bf(float f) {
  unsigned u = __builtin_bit_cast(unsigned, f);
  u = u + 0x7FFFu + ((u >> 16) & 1u);   // RNE
  return (short)(u >> 16);
}

// ---------------- mask -> bitmask ----------------
__global__ void mask_bits_kernel(const int* __restrict__ mask, unsigned* __restrict__ mbits) {
  int i = blockIdx.x * blockDim.x + threadIdx.x;   // over B*S*S = 8388608
  bool v = mask[i] != 0;
  unsigned long long bal = __ballot(v);
  int lane = threadIdx.x & 63;
  if (lane == 0)       mbits[i >> 5] = (unsigned)bal;
  else if (lane == 32) mbits[i >> 5] = (unsigned)(bal >> 32);
}

// ---------------- GEMM: out = A @ W^T + b ----------------
// A: [4096,1024] (fp32 or bf16), W: [1024,1024] fp32 row-major (rows = out col)
// OUTMODE 0: bf16 out in [B,H,S,64] head layout; OUTMODE 1: fp32 flat [4096,1024]
#define BM 128
#define BN 128
#define BK 32
#define LDT (BK + 8)   // 40 shorts = 80B row stride (16B-aligned, ~2-way banks)

template<bool ABF16, int OUTMODE>
__global__ __launch_bounds__(256) void gemm_nt(const void* __restrict__ Aptr,
                                               const float* __restrict__ Bw,
                                               const float* __restrict__ bias,
                                               void* __restrict__ outp) {
  __shared__ short lds_a[BM][LDT];
  __shared__ short lds_b[BN][LDT];
  const int tid = threadIdx.x;
  const int lane = tid & 63;
  const int wid = tid >> 6;
  const int wm = wid >> 1, wn = wid & 1;
  const int bn = blockIdx.x, bm = blockIdx.y;
  const int l15 = lane & 15, lg = lane >> 4;

  float4v acc[4][4];
#pragma unroll
  for (int m = 0; m < 4; ++m)
#pragma unroll
    for (int n = 0; n < 4; ++n) acc[m][n] = (float4v){0.f, 0.f, 0.f, 0.f};

  for (int kt = 0; kt < 1024; kt += BK) {
    if constexpr (!ABF16) {
      const float* Af = (const float*)Aptr;
#pragma unroll
      for (int it = 0; it < 4; ++it) {
        int idx = it * 1024 + tid * 4;
        int row = idx >> 5, col = idx & 31;
        float4v v = *(const float4v*)(Af + (size_t)(bm * BM + row) * 1024 + kt + col);
        short4v s;
        s[0] = f2bf(v[0]); s[1] = f2bf(v[1]); s[2] = f2bf(v[2]); s[3] = f2bf(v[3]);
        *(short4v*)&lds_a[row][col] = s;
      }
    } else {
      const short* Af = (const short*)Aptr;
#pragma unroll
      for (int it = 0; it < 2; ++it) {
        int idx = it * 2048 + tid * 8;
        int row = idx >> 5, col = idx & 31;
        *(short8*)&lds_a[row][col] =
            *(const short8*)(Af + (size_t)(bm * BM + row) * 1024 + kt + col);
      }
    }
#pragma unroll
    for (int it = 0; it < 4; ++it) {
      int idx = it * 1024 + tid * 4;
      int row = idx >> 5, col = idx & 31;
      float4v v = *(const float4v*)(Bw + (size_t)(bn * BN + row) * 1024 + kt + col);
      short4v s;
      s[0] = f2bf(v[0]); s[1] = f2bf(v[1]); s[2] = f2bf(v[2]); s[3] = f2bf(v[3]);
      *(short4v*)&lds_b[row][col] = s;
    }
    __syncthreads();

    short8 af[4], bf[4];
#pragma unroll
    for (int m = 0; m < 4; ++m)
      af[m] = *(const short8*)&lds_a[wm * 64 + m * 16 + l15][lg * 8];
#pragma unroll
    for (int n = 0; n < 4; ++n)
      bf[n] = *(const short8*)&lds_b[wn * 64 + n * 16 + l15][lg * 8];
#pragma unroll
    for (int m = 0; m < 4; ++m)
#pragma unroll
      for (int n = 0; n < 4; ++n)
        acc[m][n] = __builtin_amdgcn_mfma_f32_16x16x32_bf16(af[m], bf[n], acc[m][n], 0, 0, 0);
    __syncthreads();
  }

#pragma unroll
  for (int n = 0; n < 4; ++n) {
    int col = bn * BN + wn * 64 + n * 16 + l15;
    float bv = bias[col];
#pragma unroll
    for (int m = 0; m < 4; ++m) {
#pragma unroll
      for (int r = 0; r < 4; ++r) {
        int row = bm * BM + wm * 64 + m * 16 + lg * 4 + r;
        float val = acc[m][n][r] + bv;
        if constexpr (OUTMODE == 0) {
          int bidx = row >> 11, s = row & 2047;
          int h = col >> 6, d = col & 63;
          ((short*)outp)[(((size_t)(bidx * NUM_HEADX + h)) * SSX + s) * D_KX + d] = f2bf(val);
        } else {
          ((float*)outp)[(size_t)row * D_MODELX + col] = val;
        }
      }
    }
  }
}

// ---------------- flash attention ----------------
// grid: (B*H) * (S/16) blocks, 64 threads (1 wave). QBLK=16, KVBLK=64.
__device__ __forceinline__ int swzk(int row, int col) {  // rows of 64 shorts (128B)
  int byte = (row << 7) + (col << 1);
  return (byte ^ ((row & 7) << 4)) >> 1;
}

__global__ __launch_bounds__(64) void attn_kernel(const short* __restrict__ q_ws,
                                                  const short* __restrict__ k_ws,
                                                  const short* __restrict__ v_ws,
                                                  const unsigned* __restrict__ mbits,
                                                  short* __restrict__ attn_ws) {
  __shared__ short k_lds[64 * 64];
  __shared__ short vT_lds[64 * 64];
  __shared__ short p_lds[16 * 64];

  const int lane = threadIdx.x;
  const int l15 = lane & 15, lg = lane >> 4;
  const int bid = blockIdx.x;
  const int qt = bid & 127;      // S/16 = 128 q-tiles
  const int bh = bid >> 7;       // 0..31
  const int b = bh >> 4;
  const int h = bh & 15;

  // Q fragments: A-frag row = l15 (q row in tile), k = f*32 + lg*8
  short8 qf[2];
#pragma unroll
  for (int f = 0; f < 2; ++f)
    qf[f] = *(const short8*)(q_ws + ((size_t)bh * SSX + qt * 16 + l15) * D_KX + f * 32 + lg * 8);

  float4v acc[4];
#pragma unroll
  for (int db = 0; db < 4; ++db) acc[db] = (float4v){0.f, 0.f, 0.f, 0.f};
  float m_run[4], l_run[4];
#pragma unroll
  for (int r = 0; r < 4; ++r) { m_run[r] = -INFINITY; l_run[r] = 0.f; }

  for (int kb = 0; kb < SSX; kb += 64) {
    // stage K tile [64 ki][64 d], swizzled
#pragma unroll
    for (int it = 0; it < 8; ++it) {
      int idx = it * 512 + lane * 8;
      int ki = idx >> 6, d = idx & 63;
      short8 v = *(const short8*)(k_ws + ((size_t)bh * SSX + kb + ki) * D_KX + d);
      *(short8*)&k_lds[swzk(ki, d)] = v;
    }
    // stage V^T tile [64 d][64 ki], swizzled; rotate j to avoid bank conflicts
#pragma unroll
    for (int it = 0; it < 8; ++it) {
      int idx = it * 512 + lane * 8;
      int ki = idx >> 6, d0 = idx & 63;
      short8 v = *(const short8*)(v_ws + ((size_t)bh * SSX + kb + ki) * D_KX + d0);
#pragma unroll
      for (int j = 0; j < 8; ++j) {
        int jj = (j + (lane >> 3)) & 7;
        vT_lds[swzk(d0 + jj, ki)] = v[jj];
      }
    }
    __syncthreads();

    // mask words: row qi = lg*4 + r, bits kb..kb+63
    unsigned long long mw[4];
#pragma unroll
    for (int r = 0; r < 4; ++r)
      mw[r] = *(const unsigned long long*)(mbits +
                ((size_t)b * SSX + qt * 16 + lg * 4 + r) * (SSX / 32) + (kb >> 5));

    // QK^T: 4 ki-fragments of 16
    float p[4][4];
#pragma unroll
    for (int kf = 0; kf < 4; ++kf) {
      short8 kb0 = *(const short8*)&k_lds[swzk(kf * 16 + l15, lg * 8)];
      short8 kb1 = *(const short8*)&k_lds[swzk(kf * 16 + l15, 32 + lg * 8)];
      float4v f = (float4v){0.f, 0.f, 0.f, 0.f};
      f = __builtin_amdgcn_mfma_f32_16x16x32_bf16(qf[0], kb0, f, 0, 0, 0);
      f = __builtin_amdgcn_mfma_f32_16x16x32_bf16(qf[1], kb1, f, 0, 0, 0);
#pragma unroll
      for (int r = 0; r < 4; ++r) {
        float s = f[r] * 0.125f;
        if (!((mw[r] >> (kf * 16 + l15)) & 1ull)) s = -1e9f;
        p[kf][r] = s;
      }
    }

    // online softmax over ki (cols spread across 16 lanes + 4 frags)
    float tmax[4];
#pragma unroll
    for (int r = 0; r < 4; ++r)
      tmax[r] = fmaxf(fmaxf(p[0][r], p[1][r]), fmaxf(p[2][r], p[3][r]));
#pragma unroll
    for (int off = 1; off < 16; off <<= 1)
#pragma unroll
      for (int r = 0; r < 4; ++r) tmax[r] = fmaxf(tmax[r], __shfl_xor(tmax[r], off));

    float corr[4];
#pragma unroll
    for (int r = 0; r < 4; ++r) {
      float mn = fmaxf(m_run[r], tmax[r]);
      corr[r] = __expf(m_run[r] - mn);   // first tile: exp(-inf)=0
      m_run[r] = mn;
    }
    float psum[4] = {0.f, 0.f, 0.f, 0.f};
#pragma unroll
    for (int kf = 0; kf < 4; ++kf)
#pragma unroll
      for (int r = 0; r < 4; ++r) {
        float pv = __expf(p[kf][r] - m_run[r]);
        p[kf][r] = pv;
        psum[r] += pv;
      }
#pragma unroll
    for (int off = 1; off < 16; off <<= 1)
#pragma unroll
      for (int r = 0; r < 4; ++r) psum[r] += __shfl_xor(psum[r], off);
#pragma unroll
    for (int r = 0; r < 4; ++r) l_run[r] = l_run[r] * corr[r] + psum[r];
#pragma unroll
    for (int db = 0; db < 4; ++db)
#pragma unroll
      for (int r = 0; r < 4; ++r) acc[db][r] *= corr[r];

    // P -> LDS (bf16, swizzled): row qi = lg*4+r, col ki = kf*16+l15
#pragma unroll
    for (int kf = 0; kf < 4; ++kf)
#pragma unroll
      for (int r = 0; r < 4; ++r)
        p_lds[swzk(lg * 4 + r, kf * 16 + l15)] = f2bf(p[kf][r]);
    __syncthreads();

    // PV: acc[db] += P(16x64) * V(64x16 per db)
#pragma unroll
    for (int db = 0; db < 4; ++db) {
#pragma unroll
      for (int c = 0; c < 2; ++c) {
        short8 pa = *(const short8*)&p_lds[swzk(l15, c * 32 + lg * 8)];
        short8 vb = *(const short8*)&vT_lds[swzk(db * 16 + l15, c * 32 + lg * 8)];
        acc[db] = __builtin_amdgcn_mfma_f32_16x16x32_bf16(pa, vb, acc[db], 0, 0, 0);
      }
    }
    __syncthreads();
  }

  // epilogue: attn_ws[t][h*64 + d] bf16, t = b*S + qt*16 + lg*4 + r
#pragma unroll
  for (int db = 0; db < 4; ++db)
#pragma unroll
    for (int r = 0; r < 4; ++r) {
      float val = acc[db][r] / l_run[r];
      size_t t = (size_t)b * SSX + qt * 16 + lg * 4 + r;
      attn_ws[t * D_MODELX + h * 64 + db * 16 + l15] = f2bf(val);
    }
}

// ---------------- launcher ----------------
extern "C" void kernel_launch(void* const* d_in, const int* in_sizes, int n_in,
                              void* d_out, int out_size, void* d_ws, size_t ws_size,
                              hipStream_t stream) {
  const float* x_q = (const float*)d_in[0];
  const float* x_k = (const float*)d_in[1];
  const float* x_v = (const float*)d_in[2];
  const int*   mask = (const int*)d_in[3];
  const float* Wq = (const float*)d_in[4];
  const float* bq = (const float*)d_in[5];
  const float* Wk = (const float*)d_in[6];
  const float* bk = (const float*)d_in[7];
  const float* Wv = (const float*)d_in[8];
  const float* bv = (const float*)d_in[9];
  const float* Wo = (const float*)d_in[10];
  const float* bo = (const float*)d_in[11];

  char* ws = (char*)d_ws;
  short* q_ws    = (short*)(ws + 0);                       // 8 MB
  short* k_ws    = (short*)(ws + 8u * 1024 * 1024);        // 8 MB
  short* v_ws    = (short*)(ws + 16u * 1024 * 1024);       // 8 MB
  short* attn_ws = (short*)(ws + 24u * 1024 * 1024);       // 8 MB
  unsigned* mbits = (unsigned*)(ws + 32u * 1024 * 1024);   // 1 MB

  mask_bits_kernel<<<(BBX * SSX * SSX) / 256, 256, 0, stream>>>(mask, mbits);

  dim3 ggrid(D_MODELX / BN, M_TOK / BM);
  gemm_nt<false, 0><<<ggrid, 256, 0, stream>>>(x_q, Wq, bq, q_ws);
  gemm_nt<false, 0><<<ggrid, 256, 0, stream>>>(x_k, Wk, bk, k_ws);
  gemm_nt<false, 0><<<ggrid, 256, 0, stream>>>(x_v, Wv, bv, v_ws);

  attn_kernel<<<BBX * NUM_HEADX * (SSX / 16), 64, 0, stream>>>(q_ws, k_ws, v_ws, mbits, attn_ws);

  gemm_nt<true, 1><<<ggrid, 256, 0, stream>>>(attn_ws, Wo, bo, (float*)d_out);
}

// Round 2
// 323.364 us; speedup vs baseline: 2.1776x; 2.1776x over previous
//
#include <hip/hip_runtime.h>
#include <cstdint>
#include <cstddef>

#define D_MODELX 1024
#define NUM_HEADX 16
#define D_KX 64
#define BBX 2
#define SSX 2048
#define M_TOK 4096   // B*S

typedef __attribute__((ext_vector_type(8))) short short8;
typedef __attribute__((ext_vector_type(4))) short short4v;
typedef __attribute__((ext_vector_type(4))) float float4v;

__device__ __forceinline__ short f2bf(float f) {
  unsigned u = __builtin_bit_cast(unsigned, f);
  u = u + 0x7FFFu + ((u >> 16) & 1u);   // RNE
  return (short)(u >> 16);
}

// ---------------- mask -> bitmask ----------------
__global__ void mask_bits_kernel(const int* __restrict__ mask, unsigned* __restrict__ mbits) {
  int i = blockIdx.x * blockDim.x + threadIdx.x;   // over B*S*S = 8388608
  bool v = mask[i] != 0;
  unsigned long long bal = __ballot(v);
  int lane = threadIdx.x & 63;
  if (lane == 0)       mbits[i >> 5] = (unsigned)bal;
  else if (lane == 32) mbits[i >> 5] = (unsigned)(bal >> 32);
}

// ---------------- GEMM: out = A @ W^T + b ----------------
// A: [4096,1024] (fp32 or bf16), W: [1024,1024] fp32 row-major (rows = out col)
// OUTMODE 0: bf16 out [B,H,S,64]; OUTMODE 1: fp32 flat [4096,1024];
// OUTMODE 2: bf16 out transposed [B,H,64,S] (for V)
#define BM 128
#define BN 128
#define BK 32
#define LDT (BK + 8)   // 40 shorts = 80B row stride (16B-aligned, ~2-way banks)

template<bool ABF16, int OUTMODE>
__global__ __launch_bounds__(256) void gemm_nt(const void* __restrict__ Aptr,
                                               const float* __restrict__ Bw,
                                               const float* __restrict__ bias,
                                               void* __restrict__ outp) {
  __shared__ short lds_a[BM][LDT];
  __shared__ short lds_b[BN][LDT];
  const int tid = threadIdx.x;
  const int lane = tid & 63;
  const int wid = tid >> 6;
  const int wm = wid >> 1, wn = wid & 1;
  const int bn = blockIdx.x, bm = blockIdx.y;
  const int l15 = lane & 15, lg = lane >> 4;

  float4v acc[4][4];
#pragma unroll
  for (int m = 0; m < 4; ++m)
#pragma unroll
    for (int n = 0; n < 4; ++n) acc[m][n] = (float4v){0.f, 0.f, 0.f, 0.f};

  for (int kt = 0; kt < 1024; kt += BK) {
    if constexpr (!ABF16) {
      const float* Af = (const float*)Aptr;
#pragma unroll
      for (int it = 0; it < 4; ++it) {
        int idx = it * 1024 + tid * 4;
        int row = idx >> 5, col = idx & 31;
        float4v v = *(const float4v*)(Af + (size_t)(bm * BM + row) * 1024 + kt + col);
        short4v s;
        s[0] = f2bf(v[0]); s[1] = f2bf(v[1]); s[2] = f2bf(v[2]); s[3] = f2bf(v[3]);
        *(short4v*)&lds_a[row][col] = s;
      }
    } else {
      const short* Af = (const short*)Aptr;
#pragma unroll
      for (int it = 0; it < 2; ++it) {
        int idx = it * 2048 + tid * 8;
        int row = idx >> 5, col = idx & 31;
        *(short8*)&lds_a[row][col] =
            *(const short8*)(Af + (size_t)(bm * BM + row) * 1024 + kt + col);
      }
    }
#pragma unroll
    for (int it = 0; it < 4; ++it) {
      int idx = it * 1024 + tid * 4;
      int row = idx >> 5, col = idx & 31;
      float4v v = *(const float4v*)(Bw + (size_t)(bn * BN + row) * 1024 + kt + col);
      short4v s;
      s[0] = f2bf(v[0]); s[1] = f2bf(v[1]); s[2] = f2bf(v[2]); s[3] = f2bf(v[3]);
      *(short4v*)&lds_b[row][col] = s;
    }
    __syncthreads();

    short8 af[4], bf[4];
#pragma unroll
    for (int m = 0; m < 4; ++m)
      af[m] = *(const short8*)&lds_a[wm * 64 + m * 16 + l15][lg * 8];
#pragma unroll
    for (int n = 0; n < 4; ++n)
      bf[n] = *(const short8*)&lds_b[wn * 64 + n * 16 + l15][lg * 8];
#pragma unroll
    for (int m = 0; m < 4; ++m)
#pragma unroll
      for (int n = 0; n < 4; ++n)
        acc[m][n] = __builtin_amdgcn_mfma_f32_16x16x32_bf16(af[m], bf[n], acc[m][n], 0, 0, 0);
    __syncthreads();
  }

#pragma unroll
  for (int n = 0; n < 4; ++n) {
    int col = bn * BN + wn * 64 + n * 16 + l15;
    float bv = bias[col];
#pragma unroll
    for (int m = 0; m < 4; ++m) {
      if constexpr (OUTMODE == 2) {
        // transposed store: [B,H,64,S], 4 consecutive s per lane -> short4
        int base_row = bm * BM + wm * 64 + m * 16 + lg * 4;
        int bidx = base_row >> 11, s = base_row & 2047;
        int h = col >> 6, d = col & 63;
        short4v sv;
#pragma unroll
        for (int r = 0; r < 4; ++r) sv[r] = f2bf(acc[m][n][r] + bv);
        *(short4v*)&((short*)outp)[(((size_t)(bidx * NUM_HEADX + h)) * D_KX + d) * SSX + s] = sv;
      } else {
#pragma unroll
        for (int r = 0; r < 4; ++r) {
          int row = bm * BM + wm * 64 + m * 16 + lg * 4 + r;
          float val = acc[m][n][r] + bv;
          if constexpr (OUTMODE == 0) {
            int bidx = row >> 11, s = row & 2047;
            int h = col >> 6, d = col & 63;
            ((short*)outp)[(((size_t)(bidx * NUM_HEADX + h)) * SSX + s) * D_KX + d] = f2bf(val);
          } else {
            ((float*)outp)[(size_t)row * D_MODELX + col] = val;
          }
        }
      }
    }
  }
}

// ---------------- flash attention ----------------
// grid: (B*H) * (S/64) blocks, 256 threads (4 waves). QBLK=64 (16 rows/wave), KVBLK=64.
__device__ __forceinline__ int swzk(int row, int col) {  // rows of 64 shorts (128B)
  int byte = (row << 7) + (col << 1);
  return (byte ^ ((row & 7) << 4)) >> 1;
}

__global__ __launch_bounds__(256) void attn_kernel(const short* __restrict__ q_ws,
                                                   const short* __restrict__ k_ws,
                                                   const short* __restrict__ vT_ws,
                                                   const unsigned* __restrict__ mbits,
                                                   short* __restrict__ attn_ws) {
  __shared__ short k_lds[64 * 64];    // [ki][d] swizzled
  __shared__ short vT_lds[64 * 64];   // [d][ki] swizzled
  __shared__ short p_lds[4 * 16 * 64];  // per-wave [16][64] swizzled

  const int tid = threadIdx.x;
  const int lane = tid & 63;
  const int w = tid >> 6;
  const int l15 = lane & 15, lg = lane >> 4;
  const int bid = blockIdx.x;
  const int qt = bid & 31;       // S/64 = 32 q-tiles
  const int bh = bid >> 5;       // 0..31
  const int b = bh >> 4;

  short* pw = p_lds + w * 16 * 64;
  const int qrow = qt * 64 + w * 16;   // wave's first q row

  // Q fragments: A-frag row = l15, k = f*32 + lg*8
  short8 qf[2];
#pragma unroll
  for (int f = 0; f < 2; ++f)
    qf[f] = *(const short8*)(q_ws + ((size_t)bh * SSX + qrow + l15) * D_KX + f * 32 + lg * 8);

  float4v acc[4];
#pragma unroll
  for (int db = 0; db < 4; ++db) acc[db] = (float4v){0.f, 0.f, 0.f, 0.f};
  float m_run[4], l_run[4];
#pragma unroll
  for (int r = 0; r < 4; ++r) { m_run[r] = -INFINITY; l_run[r] = 0.f; }

  for (int kb = 0; kb < SSX; kb += 64) {
    // stage K tile [64 ki][64 d] (coalesced short8, swizzled dst)
#pragma unroll
    for (int it = 0; it < 2; ++it) {
      int idx = it * 2048 + tid * 8;
      int row = idx >> 6, col = idx & 63;
      short8 v = *(const short8*)(k_ws + ((size_t)bh * SSX + kb + row) * D_KX + col);
      *(short8*)&k_lds[swzk(row, col)] = v;
    }
    // stage V^T tile [64 d][64 ki] straight from transposed global (coalesced)
#pragma unroll
    for (int it = 0; it < 2; ++it) {
      int idx = it * 2048 + tid * 8;
      int row = idx >> 6, col = idx & 63;   // row=d, col=ki
      short8 v = *(const short8*)(vT_ws + ((size_t)bh * D_KX + row) * SSX + kb + col);
      *(short8*)&vT_lds[swzk(row, col)] = v;
    }
    __syncthreads();

    // mask words: q row = qrow + lg*4 + r, bits kb..kb+63
    unsigned long long mw[4];
#pragma unroll
    for (int r = 0; r < 4; ++r)
      mw[r] = *(const unsigned long long*)(mbits +
                ((size_t)b * SSX + qrow + lg * 4 + r) * (SSX / 32) + (kb >> 5));

    // QK^T: 4 ki-fragments of 16
    float p[4][4];
#pragma unroll
    for (int kf = 0; kf < 4; ++kf) {
      short8 kb0 = *(const short8*)&k_lds[swzk(kf * 16 + l15, lg * 8)];
      short8 kb1 = *(const short8*)&k_lds[swzk(kf * 16 + l15, 32 + lg * 8)];
      float4v f = (float4v){0.f, 0.f, 0.f, 0.f};
      f = __builtin_amdgcn_mfma_f32_16x16x32_bf16(qf[0], kb0, f, 0, 0, 0);
      f = __builtin_amdgcn_mfma_f32_16x16x32_bf16(qf[1], kb1, f, 0, 0, 0);
#pragma unroll
      for (int r = 0; r < 4; ++r) {
        float s = f[r] * 0.125f;
        if (!((mw[r] >> (kf * 16 + l15)) & 1ull)) s = -1e9f;
        p[kf][r] = s;
      }
    }

    // online softmax over ki (cols spread across 16 lanes + 4 frags)
    float tmax[4];
#pragma unroll
    for (int r = 0; r < 4; ++r)
      tmax[r] = fmaxf(fmaxf(p[0][r], p[1][r]), fmaxf(p[2][r], p[3][r]));
#pragma unroll
    for (int off = 1; off < 16; off <<= 1)
#pragma unroll
      for (int r = 0; r < 4; ++r) tmax[r] = fmaxf(tmax[r], __shfl_xor(tmax[r], off));

    float corr[4];
#pragma unroll
    for (int r = 0; r < 4; ++r) {
      float mn = fmaxf(m_run[r], tmax[r]);
      corr[r] = __expf(m_run[r] - mn);   // first tile: exp(-inf)=0
      m_run[r] = mn;
    }
    float psum[4] = {0.f, 0.f, 0.f, 0.f};
#pragma unroll
    for (int kf = 0; kf < 4; ++kf)
#pragma unroll
      for (int r = 0; r < 4; ++r) {
        float pv = __expf(p[kf][r] - m_run[r]);
        p[kf][r] = pv;
        psum[r] += pv;
      }
#pragma unroll
    for (int off = 1; off < 16; off <<= 1)
#pragma unroll
      for (int r = 0; r < 4; ++r) psum[r] += __shfl_xor(psum[r], off);
#pragma unroll
    for (int r = 0; r < 4; ++r) l_run[r] = l_run[r] * corr[r] + psum[r];
#pragma unroll
    for (int db = 0; db < 4; ++db)
#pragma unroll
      for (int r = 0; r < 4; ++r) acc[db][r] *= corr[r];

    // P -> LDS (bf16, swizzled): row qi = lg*4+r, col ki = kf*16+l15
#pragma unroll
    for (int kf = 0; kf < 4; ++kf)
#pragma unroll
      for (int r = 0; r < 4; ++r)
        pw[swzk(lg * 4 + r, kf * 16 + l15)] = f2bf(p[kf][r]);
    __syncthreads();

    // PV: acc[db] += P(16x64) * V(64x16 per db)
#pragma unroll
    for (int db = 0; db < 4; ++db) {
#pragma unroll
      for (int c = 0; c < 2; ++c) {
        short8 pa = *(const short8*)&pw[swzk(l15, c * 32 + lg * 8)];
        short8 vb = *(const short8*)&vT_lds[swzk(db * 16 + l15, c * 32 + lg * 8)];
        acc[db] = __builtin_amdgcn_mfma_f32_16x16x32_bf16(pa, vb, acc[db], 0, 0, 0);
      }
    }
    __syncthreads();
  }

  // epilogue: attn_ws[t][h*64 + d] bf16, t = b*S + qrow + lg*4 + r
  const int h = bh & 15;
#pragma unroll
  for (int db = 0; db < 4; ++db)
#pragma unroll
    for (int r = 0; r < 4; ++r) {
      float val = acc[db][r] / l_run[r];
      size_t t = (size_t)b * SSX + qrow + lg * 4 + r;
      attn_ws[t * D_MODELX + h * 64 + db * 16 + l15] = f2bf(val);
    }
}

// ---------------- launcher ----------------
extern "C" void kernel_launch(void* const* d_in, const int* in_sizes, int n_in,
                              void* d_out, int out_size, void* d_ws, size_t ws_size,
                              hipStream_t stream) {
  const float* x_q = (const float*)d_in[0];
  const float* x_k = (const float*)d_in[1];
  const float* x_v = (const float*)d_in[2];
  const int*   mask = (const int*)d_in[3];
  const float* Wq = (const float*)d_in[4];
  const float* bq = (const float*)d_in[5];
  const float* Wk = (const float*)d_in[6];
  const float* bk = (const float*)d_in[7];
  const float* Wv = (const float*)d_in[8];
  const float* bv = (const float*)d_in[9];
  const float* Wo = (const float*)d_in[10];
  const float* bo = (const float*)d_in[11];

  char* ws = (char*)d_ws;
  short* q_ws    = (short*)(ws + 0);                       // 8 MB  [B,H,S,64]
  short* k_ws    = (short*)(ws + 8u * 1024 * 1024);        // 8 MB  [B,H,S,64]
  short* vT_ws   = (short*)(ws + 16u * 1024 * 1024);       // 8 MB  [B,H,64,S]
  short* attn_ws = (short*)(ws + 24u * 1024 * 1024);       // 8 MB  [B*S,1024]
  unsigned* mbits = (unsigned*)(ws + 32u * 1024 * 1024);   // 1 MB

  mask_bits_kernel<<<(BBX * SSX * SSX) / 256, 256, 0, stream>>>(mask, mbits);

  dim3 ggrid(D_MODELX / BN, M_TOK / BM);
  gemm_nt<false, 0><<<ggrid, 256, 0, stream>>>(x_q, Wq, bq, q_ws);
  gemm_nt<false, 0><<<ggrid, 256, 0, stream>>>(x_k, Wk, bk, k_ws);
  gemm_nt<false, 2><<<ggrid, 256, 0, stream>>>(x_v, Wv, bv, vT_ws);

  attn_kernel<<<BBX * NUM_HEADX * (SSX / 64), 256, 0, stream>>>(q_ws, k_ws, vT_ws, mbits, attn_ws);

  gemm_nt<true, 1><<<ggrid, 256, 0, stream>>>(attn_ws, Wo, bo, (float*)d_out);
}

// Round 3
// 238.708 us; speedup vs baseline: 2.9498x; 1.3546x over previous
//
#include <hip/hip_runtime.h>
#include <cstdint>
#include <cstddef>

#define D_MODELX 1024
#define NUM_HEADX 16
#define D_KX 64
#define BBX 2
#define SSX 2048
#define M_TOK 4096   // B*S
#define MBYTE (1u << 20)

typedef __attribute__((ext_vector_type(8))) short short8;
typedef __attribute__((ext_vector_type(4))) short short4v;
typedef __attribute__((ext_vector_type(4))) float float4v;

__device__ __forceinline__ short f2bf(float f) {
  unsigned u = __builtin_bit_cast(unsigned, f);
  u = u + 0x7FFFu + ((u >> 16) & 1u);   // RNE
  return (short)(u >> 16);
}

// ---------------- mask -> bitmask ----------------
__global__ void mask_bits_kernel(const int* __restrict__ mask, unsigned* __restrict__ mbits) {
  int i = blockIdx.x * blockDim.x + threadIdx.x;   // over B*S*S = 8388608
  bool v = mask[i] != 0;
  unsigned long long bal = __ballot(v);
  int lane = threadIdx.x & 63;
  if (lane == 0)       mbits[i >> 5] = (unsigned)bal;
  else if (lane == 32) mbits[i >> 5] = (unsigned)(bal >> 32);
}

// ---------------- fp32 -> bf16 convert ----------------
__global__ void cvt_bf16_kernel(const float* __restrict__ in, short* __restrict__ out, int n4) {
  int i = blockIdx.x * blockDim.x + threadIdx.x;
  int stride = gridDim.x * blockDim.x;
  for (; i < n4; i += stride) {
    float4v v = ((const float4v*)in)[i];
    short4v s;
    s[0] = f2bf(v[0]); s[1] = f2bf(v[1]); s[2] = f2bf(v[2]); s[3] = f2bf(v[3]);
    ((short4v*)out)[i] = s;
  }
}

// ---------------- GEMM body: out = (A @ W^T + b) * oscale ----------------
// A: [4096,1024] bf16, W: [1024,1024] bf16 row-major (row = out col)
// mode 0: bf16 [B,H,S,64]; mode 1: fp32 flat [4096,1024]; mode 2: bf16 [B,H,64,S]
#define GBK 64
#define GLDT (GBK + 8)   // 72 shorts = 144B row stride

__device__ __forceinline__ void gemm_body(const short* __restrict__ A,
                                          const short* __restrict__ Bw,
                                          const float* __restrict__ bias,
                                          float oscale, void* __restrict__ outp, int mode) {
  __shared__ short lds_a[128][GLDT];
  __shared__ short lds_b[128][GLDT];
  const int tid = threadIdx.x;
  const int lane = tid & 63;
  const int wid = tid >> 6;
  const int wm = wid >> 1, wn = wid & 1;
  const int bn = blockIdx.x, bm = blockIdx.y;
  const int l15 = lane & 15, lg = lane >> 4;

  float4v acc[4][4];
#pragma unroll
  for (int m = 0; m < 4; ++m)
#pragma unroll
    for (int n = 0; n < 4; ++n) acc[m][n] = (float4v){0.f, 0.f, 0.f, 0.f};

  for (int kt = 0; kt < 1024; kt += GBK) {
#pragma unroll
    for (int it = 0; it < 4; ++it) {
      int idx = it * 2048 + tid * 8;
      int row = idx >> 6, col = idx & 63;
      *(short8*)&lds_a[row][col] = *(const short8*)(A + (size_t)(bm * 128 + row) * 1024 + kt + col);
      *(short8*)&lds_b[row][col] = *(const short8*)(Bw + (size_t)(bn * 128 + row) * 1024 + kt + col);
    }
    __syncthreads();

    short8 af[4][2], bf[4][2];
#pragma unroll
    for (int m = 0; m < 4; ++m) {
      af[m][0] = *(const short8*)&lds_a[wm * 64 + m * 16 + l15][lg * 8];
      af[m][1] = *(const short8*)&lds_a[wm * 64 + m * 16 + l15][32 + lg * 8];
    }
#pragma unroll
    for (int n = 0; n < 4; ++n) {
      bf[n][0] = *(const short8*)&lds_b[wn * 64 + n * 16 + l15][lg * 8];
      bf[n][1] = *(const short8*)&lds_b[wn * 64 + n * 16 + l15][32 + lg * 8];
    }
#pragma unroll
    for (int m = 0; m < 4; ++m)
#pragma unroll
      for (int n = 0; n < 4; ++n) {
        acc[m][n] = __builtin_amdgcn_mfma_f32_16x16x32_bf16(af[m][0], bf[n][0], acc[m][n], 0, 0, 0);
        acc[m][n] = __builtin_amdgcn_mfma_f32_16x16x32_bf16(af[m][1], bf[n][1], acc[m][n], 0, 0, 0);
      }
    __syncthreads();
  }

#pragma unroll
  for (int n = 0; n < 4; ++n) {
    int col = bn * 128 + wn * 64 + n * 16 + l15;
    float bv = bias[col];
#pragma unroll
    for (int m = 0; m < 4; ++m) {
      if (mode == 2) {
        int base_row = bm * 128 + wm * 64 + m * 16 + lg * 4;
        int bidx = base_row >> 11, s = base_row & 2047;
        int h = col >> 6, d = col & 63;
        short4v sv;
#pragma unroll
        for (int r = 0; r < 4; ++r) sv[r] = f2bf(acc[m][n][r] + bv);
        *(short4v*)&((short*)outp)[(((size_t)(bidx * NUM_HEADX + h)) * D_KX + d) * SSX + s] = sv;
      } else {
#pragma unroll
        for (int r = 0; r < 4; ++r) {
          int row = bm * 128 + wm * 64 + m * 16 + lg * 4 + r;
          float val = (acc[m][n][r] + bv) * oscale;
          if (mode == 0) {
            int bidx = row >> 11, s = row & 2047;
            int h = col >> 6, d = col & 63;
            ((short*)outp)[(((size_t)(bidx * NUM_HEADX + h)) * SSX + s) * D_KX + d] = f2bf(val);
          } else {
            ((float*)outp)[(size_t)row * D_MODELX + col] = val;
          }
        }
      }
    }
  }
}

// merged Q/K/V projection: grid.z selects projection (3 blocks/CU for overlap)
__global__ __launch_bounds__(256) void gemm_qkv_kernel(
    const short* __restrict__ xq, const short* __restrict__ xk, const short* __restrict__ xv,
    const short* __restrict__ wq, const short* __restrict__ wk, const short* __restrict__ wv,
    const float* __restrict__ bq, const float* __restrict__ bk, const float* __restrict__ bv,
    short* __restrict__ qo, short* __restrict__ ko, short* __restrict__ vo, float qs) {
  int z = blockIdx.z;
  const short* A = (z == 0) ? xq : (z == 1) ? xk : xv;
  const short* W = (z == 0) ? wq : (z == 1) ? wk : wv;
  const float* bi = (z == 0) ? bq : (z == 1) ? bk : bv;
  void* out = (z == 0) ? (void*)qo : (z == 1) ? (void*)ko : (void*)vo;
  float os = (z == 0) ? qs : 1.0f;
  int mode = (z == 2) ? 2 : 0;
  gemm_body(A, W, bi, os, out, mode);
}

__global__ __launch_bounds__(256) void gemm_one_kernel(const short* __restrict__ A,
                                                       const short* __restrict__ W,
                                                       const float* __restrict__ bias,
                                                       float os, void* __restrict__ out, int mode) {
  gemm_body(A, W, bias, os, out, mode);
}

// ---------------- flash attention ----------------
// grid: (B*H) * (S/64) blocks, 256 threads (4 waves). QBLK=64 (16 rows/wave), KVBLK=64.
// Q is pre-scaled by 0.125*log2e at projection -> scores are log2-domain, exp2 softmax.
__device__ __forceinline__ int swzk(int row, int col) {  // rows of 64 shorts (128B)
  int byte = (row << 7) + (col << 1);
  return (byte ^ ((row & 7) << 4)) >> 1;
}

__global__ __launch_bounds__(256) void attn_kernel(const short* __restrict__ q_ws,
                                                   const short* __restrict__ k_ws,
                                                   const short* __restrict__ vT_ws,
                                                   const unsigned* __restrict__ mbits,
                                                   short* __restrict__ attn_ws) {
  __shared__ short k_lds[2][64 * 64];
  __shared__ short vT_lds[2][64 * 64];
  __shared__ short p_lds[4][16 * 64];

  const int tid = threadIdx.x;
  const int lane = tid & 63;
  const int w = tid >> 6;
  const int l15 = lane & 15, lg = lane >> 4;
  const int bid = blockIdx.x;
  const int qt = bid & 31;       // S/64 = 32 q-tiles
  const int bh = bid >> 5;       // 0..31
  const int b = bh >> 4;
  const int h = bh & 15;

  short* pw = p_lds[w];
  const int qrow = qt * 64 + w * 16;

  const int srow = tid >> 2;            // staging row 0..63
  const int scol = (tid & 3) << 4;      // staging col base (16 shorts/thread)
  const short* Kb = k_ws + (size_t)bh * SSX * D_KX;
  const short* Vb = vT_ws + (size_t)bh * D_KX * SSX;   // [d][s]

  short8 qf[2];
#pragma unroll
  for (int f = 0; f < 2; ++f)
    qf[f] = *(const short8*)(q_ws + ((size_t)bh * SSX + qrow + l15) * D_KX + f * 32 + lg * 8);

  float4v acc[4];
#pragma unroll
  for (int db = 0; db < 4; ++db) acc[db] = (float4v){0.f, 0.f, 0.f, 0.f};
  float m_run[4], l_run[4];
#pragma unroll
  for (int r = 0; r < 4; ++r) { m_run[r] = -INFINITY; l_run[r] = 0.f; }

  short8 kr0, kr1, vr0, vr1;   // reg-staged next tile
  auto loadt = [&](int kb) {
    const short* kp = Kb + (size_t)(kb + srow) * D_KX + scol;
    kr0 = *(const short8*)kp;
    kr1 = *(const short8*)(kp + 8);
    const short* vp = Vb + (size_t)srow * SSX + kb + scol;
    vr0 = *(const short8*)vp;
    vr1 = *(const short8*)(vp + 8);
  };
  auto storet = [&](int bf) {
    *(short8*)&k_lds[bf][swzk(srow, scol)] = kr0;
    *(short8*)&k_lds[bf][swzk(srow, scol + 8)] = kr1;
    *(short8*)&vT_lds[bf][swzk(srow, scol)] = vr0;
    *(short8*)&vT_lds[bf][swzk(srow, scol + 8)] = vr1;
  };

  const unsigned* mrow = mbits + ((size_t)b * SSX + qrow + lg * 4) * (SSX / 32);
  unsigned long long mw[4], mwn[4];
#pragma unroll
  for (int r = 0; r < 4; ++r)
    mw[r] = *(const unsigned long long*)(mrow + (size_t)r * (SSX / 32));

  loadt(0);
  storet(0);
  loadt(64);
  __syncthreads();

  for (int t = 0; t < 32; ++t) {
    const int cur = t & 1;
    const short* kl = k_lds[cur];
    const short* vl = vT_lds[cur];

    // QK^T (scores already log2-domain via pre-scaled Q)
    float p[4][4];
#pragma unroll
    for (int kf = 0; kf < 4; ++kf) {
      short8 k0 = *(const short8*)&kl[swzk(kf * 16 + l15, lg * 8)];
      short8 k1 = *(const short8*)&kl[swzk(kf * 16 + l15, 32 + lg * 8)];
      float4v f = (float4v){0.f, 0.f, 0.f, 0.f};
      f = __builtin_amdgcn_mfma_f32_16x16x32_bf16(qf[0], k0, f, 0, 0, 0);
      f = __builtin_amdgcn_mfma_f32_16x16x32_bf16(qf[1], k1, f, 0, 0, 0);
#pragma unroll
      for (int r = 0; r < 4; ++r) {
        float s = f[r];
        if (!((mw[r] >> (kf * 16 + l15)) & 1ull)) s = -1e9f;
        p[kf][r] = s;
      }
    }

    // online softmax (base-2)
    float tmax[4];
#pragma unroll
    for (int r = 0; r < 4; ++r)
      tmax[r] = fmaxf(fmaxf(p[0][r], p[1][r]), fmaxf(p[2][r], p[3][r]));
#pragma unroll
    for (int off = 1; off < 16; off <<= 1)
#pragma unroll
      for (int r = 0; r < 4; ++r) tmax[r] = fmaxf(tmax[r], __shfl_xor(tmax[r], off));

    float corr[4];
#pragma unroll
    for (int r = 0; r < 4; ++r) {
      float mn = fmaxf(m_run[r], tmax[r]);
      corr[r] = __builtin_amdgcn_exp2f(m_run[r] - mn);
      m_run[r] = mn;
    }
    float psum[4] = {0.f, 0.f, 0.f, 0.f};
#pragma unroll
    for (int kf = 0; kf < 4; ++kf)
#pragma unroll
      for (int r = 0; r < 4; ++r) {
        float pv = __builtin_amdgcn_exp2f(p[kf][r] - m_run[r]);
        p[kf][r] = pv;
        psum[r] += pv;
      }
#pragma unroll
    for (int off = 1; off < 16; off <<= 1)
#pragma unroll
      for (int r = 0; r < 4; ++r) psum[r] += __shfl_xor(psum[r], off);
#pragma unroll
    for (int r = 0; r < 4; ++r) l_run[r] = l_run[r] * corr[r] + psum[r];
#pragma unroll
    for (int db = 0; db < 4; ++db)
#pragma unroll
      for (int r = 0; r < 4; ++r) acc[db][r] *= corr[r];

    // P -> per-wave LDS (same-wave DS is in-order: no barrier needed)
#pragma unroll
    for (int kf = 0; kf < 4; ++kf)
#pragma unroll
      for (int r = 0; r < 4; ++r)
        pw[swzk(lg * 4 + r, kf * 16 + l15)] = f2bf(p[kf][r]);

    // prefetch mask words for next tile
    if (t < 31) {
#pragma unroll
      for (int r = 0; r < 4; ++r)
        mwn[r] = *(const unsigned long long*)(mrow + (size_t)r * (SSX / 32) + 2 * (t + 1));
    }

    // PV
#pragma unroll
    for (int db = 0; db < 4; ++db) {
#pragma unroll
      for (int c = 0; c < 2; ++c) {
        short8 pa = *(const short8*)&pw[swzk(l15, c * 32 + lg * 8)];
        short8 vb = *(const short8*)&vl[swzk(db * 16 + l15, c * 32 + lg * 8)];
        acc[db] = __builtin_amdgcn_mfma_f32_16x16x32_bf16(pa, vb, acc[db], 0, 0, 0);
      }
    }

    // stage next tile into the other buffer; issue loads for tile t+2
    if (t < 31) storet(1 - cur);
    if (t < 30) loadt((t + 2) * 64);
    __syncthreads();
#pragma unroll
    for (int r = 0; r < 4; ++r) mw[r] = mwn[r];
  }

  // epilogue: attn_ws[t][h*64 + d] bf16
#pragma unroll
  for (int db = 0; db < 4; ++db)
#pragma unroll
    for (int r = 0; r < 4; ++r) {
      float val = acc[db][r] / l_run[r];
      size_t t = (size_t)b * SSX + qrow + lg * 4 + r;
      attn_ws[t * D_MODELX + h * 64 + db * 16 + l15] = f2bf(val);
    }
}

// ---------------- launcher ----------------
extern "C" void kernel_launch(void* const* d_in, const int* in_sizes, int n_in,
                              void* d_out, int out_size, void* d_ws, size_t ws_size,
                              hipStream_t stream) {
  const float* x_q = (const float*)d_in[0];
  const float* x_k = (const float*)d_in[1];
  const float* x_v = (const float*)d_in[2];
  const int*   mask = (const int*)d_in[3];
  const float* Wq = (const float*)d_in[4];
  const float* bq = (const float*)d_in[5];
  const float* Wk = (const float*)d_in[6];
  const float* bk = (const float*)d_in[7];
  const float* Wv = (const float*)d_in[8];
  const float* bv = (const float*)d_in[9];
  const float* Wo = (const float*)d_in[10];
  const float* bo = (const float*)d_in[11];

  const float QSCALE = 0.125f * 1.44269504089f;   // fold 1/sqrt(64) * log2(e) into Q

  char* ws = (char*)d_ws;
  short* q_ws  = (short*)(ws + 0 * MBYTE);     // 8 MB  [B,H,S,64] (log2-scaled)
  short* k_ws  = (short*)(ws + 8 * MBYTE);     // 8 MB  [B,H,S,64]
  short* vT_ws = (short*)(ws + 16 * MBYTE);    // 8 MB  [B,H,64,S]
  unsigned* mbits = (unsigned*)(ws + 24 * MBYTE);  // 1 MB

  mask_bits_kernel<<<(BBX * SSX * SSX) / 256, 256, 0, stream>>>(mask, mbits);

  dim3 ggrid(D_MODELX / 128, M_TOK / 128);
  const int NX4 = M_TOK * D_MODELX / 4;     // x convert float4 count
  const int NW4 = D_MODELX * D_MODELX / 4;  // W convert float4 count

  if (ws_size >= (size_t)56 * MBYTE) {
    short* wq_bf = (short*)(ws + 25 * MBYTE);
    short* wk_bf = (short*)(ws + 27 * MBYTE);
    short* wv_bf = (short*)(ws + 29 * MBYTE);
    short* xq_bf = (short*)(ws + 31 * MBYTE);
    short* xk_bf = (short*)(ws + 39 * MBYTE);
    short* xv_bf = (short*)(ws + 47 * MBYTE);
    short* attn_ws = (short*)(ws + 31 * MBYTE);  // aliases xq_bf (dead by attn phase)

    cvt_bf16_kernel<<<2048, 256, 0, stream>>>(x_q, xq_bf, NX4);
    cvt_bf16_kernel<<<2048, 256, 0, stream>>>(x_k, xk_bf, NX4);
    cvt_bf16_kernel<<<2048, 256, 0, stream>>>(x_v, xv_bf, NX4);
    cvt_bf16_kernel<<<1024, 256, 0, stream>>>(Wq, wq_bf, NW4);
    cvt_bf16_kernel<<<1024, 256, 0, stream>>>(Wk, wk_bf, NW4);
    cvt_bf16_kernel<<<1024, 256, 0, stream>>>(Wv, wv_bf, NW4);

    dim3 qkvgrid(D_MODELX / 128, M_TOK / 128, 3);
    gemm_qkv_kernel<<<qkvgrid, 256, 0, stream>>>(xq_bf, xk_bf, xv_bf, wq_bf, wk_bf, wv_bf,
                                                 bq, bk, bv, q_ws, k_ws, vT_ws, QSCALE);

    attn_kernel<<<BBX * NUM_HEADX * (SSX / 64), 256, 0, stream>>>(q_ws, k_ws, vT_ws, mbits, attn_ws);

    cvt_bf16_kernel<<<1024, 256, 0, stream>>>(Wo, wq_bf, NW4);
    gemm_one_kernel<<<ggrid, 256, 0, stream>>>(attn_ws, wq_bf, bo, 1.0f, d_out, 1);
  } else {
    // sequential low-footprint path (35 MB)
    short* w_bf = (short*)(ws + 25 * MBYTE);
    short* x_bf = (short*)(ws + 27 * MBYTE);
    short* attn_ws = (short*)(ws + 27 * MBYTE);  // aliases x_bf

    cvt_bf16_kernel<<<1024, 256, 0, stream>>>(Wq, w_bf, NW4);
    cvt_bf16_kernel<<<2048, 256, 0, stream>>>(x_q, x_bf, NX4);
    gemm_one_kernel<<<ggrid, 256, 0, stream>>>(x_bf, w_bf, bq, QSCALE, q_ws, 0);

    cvt_bf16_kernel<<<1024, 256, 0, stream>>>(Wk, w_bf, NW4);
    cvt_bf16_kernel<<<2048, 256, 0, stream>>>(x_k, x_bf, NX4);
    gemm_one_kernel<<<ggrid, 256, 0, stream>>>(x_bf, w_bf, bk, 1.0f, k_ws, 0);

    cvt_bf16_kernel<<<1024, 256, 0, stream>>>(Wv, w_bf, NW4);
    cvt_bf16_kernel<<<2048, 256, 0, stream>>>(x_v, x_bf, NX4);
    gemm_one_kernel<<<ggrid, 256, 0, stream>>>(x_bf, w_bf, bv, 1.0f, vT_ws, 2);

    attn_kernel<<<BBX * NUM_HEADX * (SSX / 64), 256, 0, stream>>>(q_ws, k_ws, vT_ws, mbits, attn_ws);

    cvt_bf16_kernel<<<1024, 256, 0, stream>>>(Wo, w_bf, NW4);
    gemm_one_kernel<<<ggrid, 256, 0, stream>>>(attn_ws, w_bf, bo, 1.0f, d_out, 1);
  }
}

// Round 4
// 193.234 us; speedup vs baseline: 3.6440x; 1.2353x over previous
//
#include <hip/hip_runtime.h>
#include <cstdint>
#include <cstddef>

#define D_MODELX 1024
#define NUM_HEADX 16
#define D_KX 64
#define BBX 2
#define SSX 2048
#define M_TOK 4096   // B*S
#define MBYTE (1u << 20)

typedef __attribute__((ext_vector_type(8))) short short8;
typedef __attribute__((ext_vector_type(4))) short short4v;
typedef __attribute__((ext_vector_type(4))) float float4v;

__device__ __forceinline__ short f2bf(float f) {
  unsigned u = __builtin_bit_cast(unsigned, f);
  u = u + 0x7FFFu + ((u >> 16) & 1u);   // RNE
  return (short)(u >> 16);
}

// ---------------- mask -> bitmask ----------------
__global__ void mask_bits_kernel(const int* __restrict__ mask, unsigned* __restrict__ mbits) {
  int i = blockIdx.x * blockDim.x + threadIdx.x;   // over B*S*S = 8388608
  bool v = mask[i] != 0;
  unsigned long long bal = __ballot(v);
  int lane = threadIdx.x & 63;
  if (lane == 0)       mbits[i >> 5] = (unsigned)bal;
  else if (lane == 32) mbits[i >> 5] = (unsigned)(bal >> 32);
}

// ---------------- fp32 -> bf16 converts (merged) ----------------
__global__ void cvt_w4_kernel(const float* __restrict__ w0, const float* __restrict__ w1,
                              const float* __restrict__ w2, const float* __restrict__ w3,
                              short* __restrict__ o0, short* __restrict__ o1,
                              short* __restrict__ o2, short* __restrict__ o3) {
  int z = blockIdx.y;
  const float* in = (z == 0) ? w0 : (z == 1) ? w1 : (z == 2) ? w2 : w3;
  short* out = (z == 0) ? o0 : (z == 1) ? o1 : (z == 2) ? o2 : o3;
  int i = blockIdx.x * blockDim.x + threadIdx.x;   // 1024*256 = 256K = exact
  float4v v = ((const float4v*)in)[i];
  short4v s;
  s[0] = f2bf(v[0]); s[1] = f2bf(v[1]); s[2] = f2bf(v[2]); s[3] = f2bf(v[3]);
  ((short4v*)out)[i] = s;
}

__global__ void cvt_x3_kernel(const float* __restrict__ x0, const float* __restrict__ x1,
                              const float* __restrict__ x2,
                              short* __restrict__ o0, short* __restrict__ o1,
                              short* __restrict__ o2) {
  int z = blockIdx.y;
  const float* in = (z == 0) ? x0 : (z == 1) ? x1 : x2;
  short* out = (z == 0) ? o0 : (z == 1) ? o1 : o2;
  int i = blockIdx.x * blockDim.x + threadIdx.x;   // 4096*256 = 1M = exact
  float4v v = ((const float4v*)in)[i];
  short4v s;
  s[0] = f2bf(v[0]); s[1] = f2bf(v[1]); s[2] = f2bf(v[2]); s[3] = f2bf(v[3]);
  ((short4v*)out)[i] = s;
}

// ---------------- GEMM body: out = (A @ W^T + b) * oscale ----------------
#define GBK 64
#define GLDT (GBK + 8)   // 72 shorts = 144B row stride

__device__ __forceinline__ void gemm_body(const short* __restrict__ A,
                                          const short* __restrict__ Bw,
                                          const float* __restrict__ bias,
                                          float oscale, void* __restrict__ outp, int mode) {
  __shared__ short lds_a[128][GLDT];
  __shared__ short lds_b[128][GLDT];
  const int tid = threadIdx.x;
  const int lane = tid & 63;
  const int wid = tid >> 6;
  const int wm = wid >> 1, wn = wid & 1;
  const int bn = blockIdx.x, bm = blockIdx.y;
  const int l15 = lane & 15, lg = lane >> 4;

  float4v acc[4][4];
#pragma unroll
  for (int m = 0; m < 4; ++m)
#pragma unroll
    for (int n = 0; n < 4; ++n) acc[m][n] = (float4v){0.f, 0.f, 0.f, 0.f};

  for (int kt = 0; kt < 1024; kt += GBK) {
#pragma unroll
    for (int it = 0; it < 4; ++it) {
      int idx = it * 2048 + tid * 8;
      int row = idx >> 6, col = idx & 63;
      *(short8*)&lds_a[row][col] = *(const short8*)(A + (size_t)(bm * 128 + row) * 1024 + kt + col);
      *(short8*)&lds_b[row][col] = *(const short8*)(Bw + (size_t)(bn * 128 + row) * 1024 + kt + col);
    }
    __syncthreads();

    short8 af[4][2], bf[4][2];
#pragma unroll
    for (int m = 0; m < 4; ++m) {
      af[m][0] = *(const short8*)&lds_a[wm * 64 + m * 16 + l15][lg * 8];
      af[m][1] = *(const short8*)&lds_a[wm * 64 + m * 16 + l15][32 + lg * 8];
    }
#pragma unroll
    for (int n = 0; n < 4; ++n) {
      bf[n][0] = *(const short8*)&lds_b[wn * 64 + n * 16 + l15][lg * 8];
      bf[n][1] = *(const short8*)&lds_b[wn * 64 + n * 16 + l15][32 + lg * 8];
    }
#pragma unroll
    for (int m = 0; m < 4; ++m)
#pragma unroll
      for (int n = 0; n < 4; ++n) {
        acc[m][n] = __builtin_amdgcn_mfma_f32_16x16x32_bf16(af[m][0], bf[n][0], acc[m][n], 0, 0, 0);
        acc[m][n] = __builtin_amdgcn_mfma_f32_16x16x32_bf16(af[m][1], bf[n][1], acc[m][n], 0, 0, 0);
      }
    __syncthreads();
  }

#pragma unroll
  for (int n = 0; n < 4; ++n) {
    int col = bn * 128 + wn * 64 + n * 16 + l15;
    float bv = bias[col];
#pragma unroll
    for (int m = 0; m < 4; ++m) {
      if (mode == 2) {
        int base_row = bm * 128 + wm * 64 + m * 16 + lg * 4;
        int bidx = base_row >> 11, s = base_row & 2047;
        int h = col >> 6, d = col & 63;
        short4v sv;
#pragma unroll
        for (int r = 0; r < 4; ++r) sv[r] = f2bf(acc[m][n][r] + bv);
        *(short4v*)&((short*)outp)[(((size_t)(bidx * NUM_HEADX + h)) * D_KX + d) * SSX + s] = sv;
      } else {
#pragma unroll
        for (int r = 0; r < 4; ++r) {
          int row = bm * 128 + wm * 64 + m * 16 + lg * 4 + r;
          float val = (acc[m][n][r] + bv) * oscale;
          if (mode == 0) {
            int bidx = row >> 11, s = row & 2047;
            int h = col >> 6, d = col & 63;
            ((short*)outp)[(((size_t)(bidx * NUM_HEADX + h)) * SSX + s) * D_KX + d] = f2bf(val);
          } else {
            ((float*)outp)[(size_t)row * D_MODELX + col] = val;
          }
        }
      }
    }
  }
}

__global__ __launch_bounds__(256) void gemm_qkv_kernel(
    const short* __restrict__ xq, const short* __restrict__ xk, const short* __restrict__ xv,
    const short* __restrict__ wq, const short* __restrict__ wk, const short* __restrict__ wv,
    const float* __restrict__ bq, const float* __restrict__ bk, const float* __restrict__ bv,
    short* __restrict__ qo, short* __restrict__ ko, short* __restrict__ vo, float qs) {
  int z = blockIdx.z;
  const short* A = (z == 0) ? xq : (z == 1) ? xk : xv;
  const short* W = (z == 0) ? wq : (z == 1) ? wk : wv;
  const float* bi = (z == 0) ? bq : (z == 1) ? bk : bv;
  void* out = (z == 0) ? (void*)qo : (z == 1) ? (void*)ko : (void*)vo;
  float os = (z == 0) ? qs : 1.0f;
  int mode = (z == 2) ? 2 : 0;
  gemm_body(A, W, bi, os, out, mode);
}

__global__ __launch_bounds__(256) void gemm_one_kernel(const short* __restrict__ A,
                                                       const short* __restrict__ W,
                                                       const float* __restrict__ bias,
                                                       float os, void* __restrict__ out, int mode) {
  gemm_body(A, W, bias, os, out, mode);
}

// ---------------- flash attention ----------------
// grid: (B*H)*(S/64) blocks, 256 threads (4 waves). 16 q-rows/wave, KVBLK=64.
// Q pre-scaled by 0.125*log2e -> log2-domain scores, exp2 softmax.
// Defer-max (THR=8) + lazy l-sum + raw-score tmax (mask applied post-exp2).
__device__ __forceinline__ int swzk(int row, int col) {  // rows of 64 shorts (128B)
  int byte = (row << 7) + (col << 1);
  return (byte ^ ((row & 7) << 4)) >> 1;
}

__global__ __launch_bounds__(256) void attn_kernel(const short* __restrict__ q_ws,
                                                   const short* __restrict__ k_ws,
                                                   const short* __restrict__ vT_ws,
                                                   const unsigned* __restrict__ mbits,
                                                   short* __restrict__ attn_ws) {
  __shared__ short k_lds[2][64 * 64];
  __shared__ short vT_lds[2][64 * 64];
  __shared__ short p_lds[4][16 * 64];

  const int tid = threadIdx.x;
  const int lane = tid & 63;
  const int w = tid >> 6;
  const int l15 = lane & 15, lg = lane >> 4;
  const int bid = blockIdx.x;
  const int qt = bid & 31;
  const int bh = bid >> 5;
  const int b = bh >> 4;
  const int h = bh & 15;

  short* pw = p_lds[w];
  const int qrow = qt * 64 + w * 16;

  const int srow = tid >> 2;
  const int scol = (tid & 3) << 4;
  const short* Kb = k_ws + (size_t)bh * SSX * D_KX;
  const short* Vb = vT_ws + (size_t)bh * D_KX * SSX;

  short8 qf[2];
#pragma unroll
  for (int f = 0; f < 2; ++f)
    qf[f] = *(const short8*)(q_ws + ((size_t)bh * SSX + qrow + l15) * D_KX + f * 32 + lg * 8);

  float4v acc[4];
#pragma unroll
  for (int db = 0; db < 4; ++db) acc[db] = (float4v){0.f, 0.f, 0.f, 0.f};
  float m_run[4], l_part[4];
#pragma unroll
  for (int r = 0; r < 4; ++r) { m_run[r] = -INFINITY; l_part[r] = 0.f; }

  short8 kr0, kr1, vr0, vr1;
  auto loadt = [&](int kb) {
    const short* kp = Kb + (size_t)(kb + srow) * D_KX + scol;
    kr0 = *(const short8*)kp;
    kr1 = *(const short8*)(kp + 8);
    const short* vp = Vb + (size_t)srow * SSX + kb + scol;
    vr0 = *(const short8*)vp;
    vr1 = *(const short8*)(vp + 8);
  };
  auto storet = [&](int bf) {
    *(short8*)&k_lds[bf][swzk(srow, scol)] = kr0;
    *(short8*)&k_lds[bf][swzk(srow, scol + 8)] = kr1;
    *(short8*)&vT_lds[bf][swzk(srow, scol)] = vr0;
    *(short8*)&vT_lds[bf][swzk(srow, scol + 8)] = vr1;
  };

  const unsigned* mrow = mbits + ((size_t)b * SSX + qrow + lg * 4) * (SSX / 32);
  unsigned long long mw[4], mwn[4];
#pragma unroll
  for (int r = 0; r < 4; ++r)
    mw[r] = *(const unsigned long long*)(mrow + (size_t)r * (SSX / 32));

  loadt(0);
  storet(0);
  loadt(64);
  __syncthreads();

  for (int t = 0; t < 32; ++t) {
    const int cur = t & 1;
    const short* kl = k_lds[cur];
    const short* vl = vT_lds[cur];

    // QK^T (raw log2-domain scores; mask NOT applied here)
    float p[4][4];
#pragma unroll
    for (int kf = 0; kf < 4; ++kf) {
      short8 k0 = *(const short8*)&kl[swzk(kf * 16 + l15, lg * 8)];
      short8 k1 = *(const short8*)&kl[swzk(kf * 16 + l15, 32 + lg * 8)];
      float4v f = (float4v){0.f, 0.f, 0.f, 0.f};
      f = __builtin_amdgcn_mfma_f32_16x16x32_bf16(qf[0], k0, f, 0, 0, 0);
      f = __builtin_amdgcn_mfma_f32_16x16x32_bf16(qf[1], k1, f, 0, 0, 0);
#pragma unroll
      for (int r = 0; r < 4; ++r) p[kf][r] = f[r];
    }

    // early staging + mask prefetch: hide global latency under softmax+PV
    if (t < 31) storet(1 - cur);
    if (t < 30) loadt((t + 2) * 64);
    if (t < 31) {
#pragma unroll
      for (int r = 0; r < 4; ++r)
        mwn[r] = *(const unsigned long long*)(mrow + (size_t)r * (SSX / 32) + 2 * (t + 1));
    }

    // per-lane raw tile max; defer-max check (THR=8 in log2 domain)
    float tmax[4];
#pragma unroll
    for (int r = 0; r < 4; ++r)
      tmax[r] = fmaxf(fmaxf(p[0][r], p[1][r]), fmaxf(p[2][r], p[3][r]));
    float dm = tmax[0] - m_run[0];
#pragma unroll
    for (int r = 1; r < 4; ++r) dm = fmaxf(dm, tmax[r] - m_run[r]);
    if (!__all(dm <= 8.0f)) {
      // full path: reduce max across 16-lane row group, rescale state
#pragma unroll
      for (int off = 1; off < 16; off <<= 1)
#pragma unroll
        for (int r = 0; r < 4; ++r) tmax[r] = fmaxf(tmax[r], __shfl_xor(tmax[r], off));
#pragma unroll
      for (int r = 0; r < 4; ++r) {
        float mn = fmaxf(m_run[r], tmax[r]);
        float corr = __builtin_amdgcn_exp2f(m_run[r] - mn);
        m_run[r] = mn;
        l_part[r] *= corr;
#pragma unroll
        for (int db = 0; db < 4; ++db) acc[db][r] *= corr;
      }
    }

    // pre-shifted mask words: bit0 = kf0, bit16 = kf1 (lo); kf2/kf3 (hi)
    unsigned lo_sh[4], hi_sh[4];
#pragma unroll
    for (int r = 0; r < 4; ++r) {
      lo_sh[r] = ((unsigned)mw[r]) >> l15;
      hi_sh[r] = ((unsigned)(mw[r] >> 32)) >> l15;
    }

    // exp2, mask-zero, lazy-l accumulate, write P
#pragma unroll
    for (int kf = 0; kf < 4; ++kf)
#pragma unroll
      for (int r = 0; r < 4; ++r) {
        float pv = __builtin_amdgcn_exp2f(p[kf][r] - m_run[r]);
        unsigned bit = (kf == 0) ? (lo_sh[r] & 1u) : (kf == 1) ? (lo_sh[r] & 0x10000u)
                     : (kf == 2) ? (hi_sh[r] & 1u) : (hi_sh[r] & 0x10000u);
        pv = bit ? pv : 0.0f;
        l_part[r] += pv;
        pw[swzk(lg * 4 + r, kf * 16 + l15)] = f2bf(pv);
      }

    // PV
#pragma unroll
    for (int db = 0; db < 4; ++db) {
#pragma unroll
      for (int c = 0; c < 2; ++c) {
        short8 pa = *(const short8*)&pw[swzk(l15, c * 32 + lg * 8)];
        short8 vb = *(const short8*)&vl[swzk(db * 16 + l15, c * 32 + lg * 8)];
        acc[db] = __builtin_amdgcn_mfma_f32_16x16x32_bf16(pa, vb, acc[db], 0, 0, 0);
      }
    }

    __syncthreads();
    if (t < 31) {
#pragma unroll
      for (int r = 0; r < 4; ++r) mw[r] = mwn[r];
    }
  }

  // final l reduction (once) + epilogue
#pragma unroll
  for (int off = 1; off < 16; off <<= 1)
#pragma unroll
    for (int r = 0; r < 4; ++r) l_part[r] += __shfl_xor(l_part[r], off);
  float inv[4];
#pragma unroll
  for (int r = 0; r < 4; ++r) inv[r] = 1.0f / l_part[r];

#pragma unroll
  for (int db = 0; db < 4; ++db)
#pragma unroll
    for (int r = 0; r < 4; ++r) {
      float val = acc[db][r] * inv[r];
      size_t t = (size_t)b * SSX + qrow + lg * 4 + r;
      attn_ws[t * D_MODELX + h * 64 + db * 16 + l15] = f2bf(val);
    }
}

// ---------------- launcher ----------------
extern "C" void kernel_launch(void* const* d_in, const int* in_sizes, int n_in,
                              void* d_out, int out_size, void* d_ws, size_t ws_size,
                              hipStream_t stream) {
  const float* x_q = (const float*)d_in[0];
  const float* x_k = (const float*)d_in[1];
  const float* x_v = (const float*)d_in[2];
  const int*   mask = (const int*)d_in[3];
  const float* Wq = (const float*)d_in[4];
  const float* bq = (const float*)d_in[5];
  const float* Wk = (const float*)d_in[6];
  const float* bk = (const float*)d_in[7];
  const float* Wv = (const float*)d_in[8];
  const float* bv = (const float*)d_in[9];
  const float* Wo = (const float*)d_in[10];
  const float* bo = (const float*)d_in[11];

  const float QSCALE = 0.125f * 1.44269504089f;

  char* ws = (char*)d_ws;
  short* q_ws  = (short*)(ws + 0 * MBYTE);
  short* k_ws  = (short*)(ws + 8 * MBYTE);
  short* vT_ws = (short*)(ws + 16 * MBYTE);

  dim3 ggrid(D_MODELX / 128, M_TOK / 128);

  if (ws_size >= (size_t)56 * MBYTE) {
    short* wq_bf = (short*)(ws + 24 * MBYTE);
    short* wk_bf = (short*)(ws + 26 * MBYTE);
    short* wv_bf = (short*)(ws + 28 * MBYTE);
    short* wo_bf = (short*)(ws + 30 * MBYTE);
    short* xq_bf = (short*)(ws + 32 * MBYTE);
    short* xk_bf = (short*)(ws + 40 * MBYTE);
    short* xv_bf = (short*)(ws + 48 * MBYTE);
    short* attn_ws = (short*)(ws + 32 * MBYTE);          // aliases xq_bf (dead after qkv gemm)
    unsigned* mbits = (unsigned*)(ws + 40 * MBYTE);      // aliases xk_bf (dead after qkv gemm)

    cvt_w4_kernel<<<dim3(1024, 4), 256, 0, stream>>>(Wq, Wk, Wv, Wo, wq_bf, wk_bf, wv_bf, wo_bf);
    cvt_x3_kernel<<<dim3(4096, 3), 256, 0, stream>>>(x_q, x_k, x_v, xq_bf, xk_bf, xv_bf);

    dim3 qkvgrid(D_MODELX / 128, M_TOK / 128, 3);
    gemm_qkv_kernel<<<qkvgrid, 256, 0, stream>>>(xq_bf, xk_bf, xv_bf, wq_bf, wk_bf, wv_bf,
                                                 bq, bk, bv, q_ws, k_ws, vT_ws, QSCALE);

    mask_bits_kernel<<<(BBX * SSX * SSX) / 256, 256, 0, stream>>>(mask, mbits);

    attn_kernel<<<BBX * NUM_HEADX * (SSX / 64), 256, 0, stream>>>(q_ws, k_ws, vT_ws, mbits, attn_ws);

    gemm_one_kernel<<<ggrid, 256, 0, stream>>>(attn_ws, wo_bf, bo, 1.0f, d_out, 1);
  } else {
    // sequential low-footprint path (35 MB)
    unsigned* mbits = (unsigned*)(ws + 24 * MBYTE);
    short* w_bf = (short*)(ws + 25 * MBYTE);
    short* x_bf = (short*)(ws + 27 * MBYTE);
    short* attn_ws = (short*)(ws + 27 * MBYTE);  // aliases x_bf
    const int NX4 = M_TOK * D_MODELX / 4;
    const int NW4 = D_MODELX * D_MODELX / 4;

    mask_bits_kernel<<<(BBX * SSX * SSX) / 256, 256, 0, stream>>>(mask, mbits);

    cvt_w4_kernel<<<dim3(1024, 1), 256, 0, stream>>>(Wq, Wq, Wq, Wq, w_bf, w_bf, w_bf, w_bf);
    cvt_x3_kernel<<<dim3(4096, 1), 256, 0, stream>>>(x_q, x_q, x_q, x_bf, x_bf, x_bf);
    gemm_one_kernel<<<ggrid, 256, 0, stream>>>(x_bf, w_bf, bq, QSCALE, q_ws, 0);

    cvt_w4_kernel<<<dim3(1024, 1), 256, 0, stream>>>(Wk, Wk, Wk, Wk, w_bf, w_bf, w_bf, w_bf);
    cvt_x3_kernel<<<dim3(4096, 1), 256, 0, stream>>>(x_k, x_k, x_k, x_bf, x_bf, x_bf);
    gemm_one_kernel<<<ggrid, 256, 0, stream>>>(x_bf, w_bf, bk, 1.0f, k_ws, 0);

    cvt_w4_kernel<<<dim3(1024, 1), 256, 0, stream>>>(Wv, Wv, Wv, Wv, w_bf, w_bf, w_bf, w_bf);
    cvt_x3_kernel<<<dim3(4096, 1), 256, 0, stream>>>(x_v, x_v, x_v, x_bf, x_bf, x_bf);
    gemm_one_kernel<<<ggrid, 256, 0, stream>>>(x_bf, w_bf, bv, 1.0f, vT_ws, 2);

    attn_kernel<<<BBX * NUM_HEADX * (SSX / 64), 256, 0, stream>>>(q_ws, k_ws, vT_ws, mbits, attn_ws);

    cvt_w4_kernel<<<dim3(1024, 1), 256, 0, stream>>>(Wo, Wo, Wo, Wo, w_bf, w_bf, w_bf, w_bf);
    gemm_one_kernel<<<ggrid, 256, 0, stream>>>(attn_ws, w_bf, bo, 1.0f, d_out, 1);
  }
}

// Round 5
// 172.814 us; speedup vs baseline: 4.0746x; 1.1182x over previous
//
#include <hip/hip_runtime.h>
#include <cstdint>
#include <cstddef>

#define D_MODELX 1024
#define NUM_HEADX 16
#define D_KX 64
#define BBX 2
#define SSX 2048
#define M_TOK 4096   // B*S
#define MBYTE (1u << 20)

typedef __attribute__((ext_vector_type(8))) short short8;
typedef __attribute__((ext_vector_type(4))) short short4v;
typedef __attribute__((ext_vector_type(4))) float float4v;

__device__ __forceinline__ short f2bf(float f) {
  unsigned u = __builtin_bit_cast(unsigned, f);
  u = u + 0x7FFFu + ((u >> 16) & 1u);   // RNE
  return (short)(u >> 16);
}

// ---------------- mask -> bitmask ----------------
__global__ void mask_bits_kernel(const int* __restrict__ mask, unsigned* __restrict__ mbits) {
  int i = blockIdx.x * blockDim.x + threadIdx.x;   // over B*S*S = 8388608
  bool v = mask[i] != 0;
  unsigned long long bal = __ballot(v);
  int lane = threadIdx.x & 63;
  if (lane == 0)       mbits[i >> 5] = (unsigned)bal;
  else if (lane == 32) mbits[i >> 5] = (unsigned)(bal >> 32);
}

// ---------------- fp32 -> bf16 converts (merged) ----------------
__global__ void cvt_w4_kernel(const float* __restrict__ w0, const float* __restrict__ w1,
                              const float* __restrict__ w2, const float* __restrict__ w3,
                              short* __restrict__ o0, short* __restrict__ o1,
                              short* __restrict__ o2, short* __restrict__ o3) {
  int z = blockIdx.y;
  const float* in = (z == 0) ? w0 : (z == 1) ? w1 : (z == 2) ? w2 : w3;
  short* out = (z == 0) ? o0 : (z == 1) ? o1 : (z == 2) ? o2 : o3;
  int i = blockIdx.x * blockDim.x + threadIdx.x;   // 1024*256 = 256K = exact
  float4v v = ((const float4v*)in)[i];
  short4v s;
  s[0] = f2bf(v[0]); s[1] = f2bf(v[1]); s[2] = f2bf(v[2]); s[3] = f2bf(v[3]);
  ((short4v*)out)[i] = s;
}

__global__ void cvt_x3_kernel(const float* __restrict__ x0, const float* __restrict__ x1,
                              const float* __restrict__ x2,
                              short* __restrict__ o0, short* __restrict__ o1,
                              short* __restrict__ o2) {
  int z = blockIdx.y;
  const float* in = (z == 0) ? x0 : (z == 1) ? x1 : x2;
  short* out = (z == 0) ? o0 : (z == 1) ? o1 : o2;
  int i = blockIdx.x * blockDim.x + threadIdx.x;   // 4096*256 = 1M = exact
  float4v v = ((const float4v*)in)[i];
  short4v s;
  s[0] = f2bf(v[0]); s[1] = f2bf(v[1]); s[2] = f2bf(v[2]); s[3] = f2bf(v[3]);
  ((short4v*)out)[i] = s;
}

// ---------------- GEMM body: out = (A @ W^T + b) * oscale ----------------
#define GBK 64
#define GLDT (GBK + 8)   // 72 shorts = 144B row stride

__device__ __forceinline__ void gemm_body(const short* __restrict__ A,
                                          const short* __restrict__ Bw,
                                          const float* __restrict__ bias,
                                          float oscale, void* __restrict__ outp, int mode) {
  __shared__ short lds_a[128][GLDT];
  __shared__ short lds_b[128][GLDT];
  const int tid = threadIdx.x;
  const int lane = tid & 63;
  const int wid = tid >> 6;
  const int wm = wid >> 1, wn = wid & 1;
  const int bn = blockIdx.x, bm = blockIdx.y;
  const int l15 = lane & 15, lg = lane >> 4;

  float4v acc[4][4];
#pragma unroll
  for (int m = 0; m < 4; ++m)
#pragma unroll
    for (int n = 0; n < 4; ++n) acc[m][n] = (float4v){0.f, 0.f, 0.f, 0.f};

  for (int kt = 0; kt < 1024; kt += GBK) {
#pragma unroll
    for (int it = 0; it < 4; ++it) {
      int idx = it * 2048 + tid * 8;
      int row = idx >> 6, col = idx & 63;
      *(short8*)&lds_a[row][col] = *(const short8*)(A + (size_t)(bm * 128 + row) * 1024 + kt + col);
      *(short8*)&lds_b[row][col] = *(const short8*)(Bw + (size_t)(bn * 128 + row) * 1024 + kt + col);
    }
    __syncthreads();

    short8 af[4][2], bf[4][2];
#pragma unroll
    for (int m = 0; m < 4; ++m) {
      af[m][0] = *(const short8*)&lds_a[wm * 64 + m * 16 + l15][lg * 8];
      af[m][1] = *(const short8*)&lds_a[wm * 64 + m * 16 + l15][32 + lg * 8];
    }
#pragma unroll
    for (int n = 0; n < 4; ++n) {
      bf[n][0] = *(const short8*)&lds_b[wn * 64 + n * 16 + l15][lg * 8];
      bf[n][1] = *(const short8*)&lds_b[wn * 64 + n * 16 + l15][32 + lg * 8];
    }
#pragma unroll
    for (int m = 0; m < 4; ++m)
#pragma unroll
      for (int n = 0; n < 4; ++n) {
        acc[m][n] = __builtin_amdgcn_mfma_f32_16x16x32_bf16(af[m][0], bf[n][0], acc[m][n], 0, 0, 0);
        acc[m][n] = __builtin_amdgcn_mfma_f32_16x16x32_bf16(af[m][1], bf[n][1], acc[m][n], 0, 0, 0);
      }
    __syncthreads();
  }

#pragma unroll
  for (int n = 0; n < 4; ++n) {
    int col = bn * 128 + wn * 64 + n * 16 + l15;
    float bv = bias[col];
#pragma unroll
    for (int m = 0; m < 4; ++m) {
      if (mode == 2) {
        int base_row = bm * 128 + wm * 64 + m * 16 + lg * 4;
        int bidx = base_row >> 11, s = base_row & 2047;
        int h = col >> 6, d = col & 63;
        short4v sv;
#pragma unroll
        for (int r = 0; r < 4; ++r) sv[r] = f2bf(acc[m][n][r] + bv);
        *(short4v*)&((short*)outp)[(((size_t)(bidx * NUM_HEADX + h)) * D_KX + d) * SSX + s] = sv;
      } else {
#pragma unroll
        for (int r = 0; r < 4; ++r) {
          int row = bm * 128 + wm * 64 + m * 16 + lg * 4 + r;
          float val = (acc[m][n][r] + bv) * oscale;
          if (mode == 0) {
            int bidx = row >> 11, s = row & 2047;
            int h = col >> 6, d = col & 63;
            ((short*)outp)[(((size_t)(bidx * NUM_HEADX + h)) * SSX + s) * D_KX + d] = f2bf(val);
          } else {
            ((float*)outp)[(size_t)row * D_MODELX + col] = val;
          }
        }
      }
    }
  }
}

__global__ __launch_bounds__(256) void gemm_qkv_kernel(
    const short* __restrict__ xq, const short* __restrict__ xk, const short* __restrict__ xv,
    const short* __restrict__ wq, const short* __restrict__ wk, const short* __restrict__ wv,
    const float* __restrict__ bq, const float* __restrict__ bk, const float* __restrict__ bv,
    short* __restrict__ qo, short* __restrict__ ko, short* __restrict__ vo, float qs) {
  int z = blockIdx.z;
  const short* A = (z == 0) ? xq : (z == 1) ? xk : xv;
  const short* W = (z == 0) ? wq : (z == 1) ? wk : wv;
  const float* bi = (z == 0) ? bq : (z == 1) ? bk : bv;
  void* out = (z == 0) ? (void*)qo : (z == 1) ? (void*)ko : (void*)vo;
  float os = (z == 0) ? qs : 1.0f;
  int mode = (z == 2) ? 2 : 0;
  gemm_body(A, W, bi, os, out, mode);
}

__global__ __launch_bounds__(256) void gemm_one_kernel(const short* __restrict__ A,
                                                       const short* __restrict__ W,
                                                       const float* __restrict__ bias,
                                                       float os, void* __restrict__ out, int mode) {
  gemm_body(A, W, bias, os, out, mode);
}

// ---------------- flash attention (swapped-operand, scalar-per-lane softmax) ----------------
// grid: (B*H)*(S/64) blocks, 256 threads (4 waves). 16 q-rows/wave (q = l15), KVBLK=64.
// S^T = mfma(K_frag, Q_frag): lane holds scores for q=l15, k = kf*16 + lg*4 + r.
// O^T = mfma(V^T_frag, P_frag): acc[db][r] = O[q=l15][d = db*16 + lg*4 + r].
__device__ __forceinline__ int swzk(int row, int col) {  // rows of 64 shorts (128B)
  int byte = (row << 7) + (col << 1);
  return (byte ^ ((row & 7) << 4)) >> 1;
}

__global__ __launch_bounds__(256) void attn_kernel(const short* __restrict__ q_ws,
                                                   const short* __restrict__ k_ws,
                                                   const short* __restrict__ vT_ws,
                                                   const unsigned* __restrict__ mbits,
                                                   short* __restrict__ attn_ws) {
  __shared__ short k_lds[2][64 * 64];
  __shared__ short vT_lds[2][64 * 64];
  __shared__ short p_lds[4][16 * 64];

  const int tid = threadIdx.x;
  const int lane = tid & 63;
  const int w = tid >> 6;
  const int l15 = lane & 15, lg = lane >> 4;
  // XCD-aware bijective swizzle: 1024 blocks = 8 XCDs x 128; each XCD owns 4 heads
  const int bid0 = blockIdx.x;
  const int bid = ((bid0 & 7) << 7) | (bid0 >> 3);
  const int qt = bid & 31;
  const int bh = bid >> 5;
  const int b = bh >> 4;
  const int h = bh & 15;

  short* pw = p_lds[w];
  const int qrow = qt * 64 + w * 16;

  const int srow = tid >> 2;
  const int scol = (tid & 3) << 4;
  const short* Kb = k_ws + (size_t)bh * SSX * D_KX;
  const short* Vb = vT_ws + (size_t)bh * D_KX * SSX;

  // Q fragment (B-operand): lane holds Q[q=l15][d = c*32 + lg*8 + j]
  short8 qf[2];
#pragma unroll
  for (int f = 0; f < 2; ++f)
    qf[f] = *(const short8*)(q_ws + ((size_t)bh * SSX + qrow + l15) * D_KX + f * 32 + lg * 8);

  float4v acc[4];
#pragma unroll
  for (int db = 0; db < 4; ++db) acc[db] = (float4v){0.f, 0.f, 0.f, 0.f};
  float m_run = -INFINITY, l_part = 0.f;

  short8 kr0, kr1, vr0, vr1;
  auto loadt = [&](int kb) {
    const short* kp = Kb + (size_t)(kb + srow) * D_KX + scol;
    kr0 = *(const short8*)kp;
    kr1 = *(const short8*)(kp + 8);
    const short* vp = Vb + (size_t)srow * SSX + kb + scol;
    vr0 = *(const short8*)vp;
    vr1 = *(const short8*)(vp + 8);
  };
  auto storet = [&](int bf) {
    *(short8*)&k_lds[bf][swzk(srow, scol)] = kr0;
    *(short8*)&k_lds[bf][swzk(srow, scol + 8)] = kr1;
    *(short8*)&vT_lds[bf][swzk(srow, scol)] = vr0;
    *(short8*)&vT_lds[bf][swzk(srow, scol + 8)] = vr1;
  };

  // one mask word per lane: q-row = qrow + l15
  const unsigned* mrow = mbits + ((size_t)b * SSX + qrow + l15) * (SSX / 32);
  unsigned long long mw = *(const unsigned long long*)mrow, mwn;

  loadt(0);
  storet(0);
  loadt(64);
  __syncthreads();

  for (int t = 0; t < 32; ++t) {
    const int cur = t & 1;
    const short* kl = k_lds[cur];
    const short* vl = vT_lds[cur];

    // S^T = K * Q^T: p[kf][r] = score(q=l15, k = kf*16 + lg*4 + r), log2-domain
    float p[4][4];
#pragma unroll
    for (int kf = 0; kf < 4; ++kf) {
      short8 k0 = *(const short8*)&kl[swzk(kf * 16 + l15, lg * 8)];
      short8 k1 = *(const short8*)&kl[swzk(kf * 16 + l15, 32 + lg * 8)];
      float4v f = (float4v){0.f, 0.f, 0.f, 0.f};
      f = __builtin_amdgcn_mfma_f32_16x16x32_bf16(k0, qf[0], f, 0, 0, 0);
      f = __builtin_amdgcn_mfma_f32_16x16x32_bf16(k1, qf[1], f, 0, 0, 0);
#pragma unroll
      for (int r = 0; r < 4; ++r) p[kf][r] = f[r];
    }

    // early staging + mask prefetch: hide global latency under softmax+PV
    if (t < 31) storet(1 - cur);
    if (t < 30) loadt((t + 2) * 64);
    if (t < 31) mwn = *(const unsigned long long*)(mrow + 2 * (t + 1));

    // per-lane raw tile max (q=l15 fully lane-local); defer-max THR=8 (log2)
    float tmax = fmaxf(fmaxf(fmaxf(p[0][0], p[0][1]), fmaxf(p[0][2], p[0][3])),
                       fmaxf(fmaxf(p[1][0], p[1][1]), fmaxf(p[1][2], p[1][3])));
    tmax = fmaxf(tmax, fmaxf(fmaxf(fmaxf(p[2][0], p[2][1]), fmaxf(p[2][2], p[2][3])),
                             fmaxf(fmaxf(p[3][0], p[3][1]), fmaxf(p[3][2], p[3][3]))));
    if (!__all(tmax - m_run <= 8.0f)) {
      // full path: reduce max across the 4 lg-groups holding this q-row
      tmax = fmaxf(tmax, __shfl_xor(tmax, 16));
      tmax = fmaxf(tmax, __shfl_xor(tmax, 32));
      float mn = fmaxf(m_run, tmax);
      float corr = __builtin_amdgcn_exp2f(m_run - mn);
      m_run = mn;
      l_part *= corr;
#pragma unroll
      for (int db = 0; db < 4; ++db)
#pragma unroll
        for (int r = 0; r < 4; ++r) acc[db][r] *= corr;
    }

    // mask bits for this lane's 16 k's: bit (kf*16 + r) of (mw >> lg*4)
    unsigned long long sh = mw >> (lg * 4);
    unsigned mlo = (unsigned)sh, mhi = (unsigned)(sh >> 32);

    // exp2, mask-zero, lazy-l, pack to bf16 pairs, write P row q=l15
#pragma unroll
    for (int kf = 0; kf < 4; ++kf) {
      float pv_[4];
#pragma unroll
      for (int r = 0; r < 4; ++r) {
        float pv = __builtin_amdgcn_exp2f(p[kf][r] - m_run);
        unsigned bit = (kf < 2 ? mlo : mhi) & (1u << ((kf & 1) * 16 + r));
        pv = bit ? pv : 0.0f;
        l_part += pv;
        pv_[r] = pv;
      }
      unsigned u0, u1;
      asm("v_cvt_pk_bf16_f32 %0, %1, %2" : "=v"(u0) : "v"(pv_[0]), "v"(pv_[1]));
      asm("v_cvt_pk_bf16_f32 %0, %1, %2" : "=v"(u1) : "v"(pv_[2]), "v"(pv_[3]));
      uint2 w2;
      w2.x = u0; w2.y = u1;
      *(uint2*)&pw[swzk(l15, kf * 16 + lg * 4)] = w2;
    }

    // O^T += V^T * P^T: acc[db][r] = O[q=l15][d=db*16+lg*4+r]
#pragma unroll
    for (int db = 0; db < 4; ++db) {
#pragma unroll
      for (int c = 0; c < 2; ++c) {
        short8 vb = *(const short8*)&vl[swzk(db * 16 + l15, c * 32 + lg * 8)];
        short8 pa = *(const short8*)&pw[swzk(l15, c * 32 + lg * 8)];
        acc[db] = __builtin_amdgcn_mfma_f32_16x16x32_bf16(vb, pa, acc[db], 0, 0, 0);
      }
    }

    __syncthreads();
    mw = mwn;
  }

  // final l reduction across the 4 lg-groups + epilogue (4 consecutive d per db)
  l_part += __shfl_xor(l_part, 16);
  l_part += __shfl_xor(l_part, 32);
  float inv = 1.0f / l_part;

  size_t ttok = (size_t)b * SSX + qrow + l15;
#pragma unroll
  for (int db = 0; db < 4; ++db) {
    short4v sv;
#pragma unroll
    for (int r = 0; r < 4; ++r) sv[r] = f2bf(acc[db][r] * inv);
    *(short4v*)&attn_ws[ttok * D_MODELX + h * 64 + db * 16 + lg * 4] = sv;
  }
}

// ---------------- launcher ----------------
extern "C" void kernel_launch(void* const* d_in, const int* in_sizes, int n_in,
                              void* d_out, int out_size, void* d_ws, size_t ws_size,
                              hipStream_t stream) {
  const float* x_q = (const float*)d_in[0];
  const float* x_k = (const float*)d_in[1];
  const float* x_v = (const float*)d_in[2];
  const int*   mask = (const int*)d_in[3];
  const float* Wq = (const float*)d_in[4];
  const float* bq = (const float*)d_in[5];
  const float* Wk = (const float*)d_in[6];
  const float* bk = (const float*)d_in[7];
  const float* Wv = (const float*)d_in[8];
  const float* bv = (const float*)d_in[9];
  const float* Wo = (const float*)d_in[10];
  const float* bo = (const float*)d_in[11];

  const float QSCALE = 0.125f * 1.44269504089f;

  char* ws = (char*)d_ws;
  short* q_ws  = (short*)(ws + 0 * MBYTE);
  short* k_ws  = (short*)(ws + 8 * MBYTE);
  short* vT_ws = (short*)(ws + 16 * MBYTE);

  dim3 ggrid(D_MODELX / 128, M_TOK / 128);

  if (ws_size >= (size_t)56 * MBYTE) {
    short* wq_bf = (short*)(ws + 24 * MBYTE);
    short* wk_bf = (short*)(ws + 26 * MBYTE);
    short* wv_bf = (short*)(ws + 28 * MBYTE);
    short* wo_bf = (short*)(ws + 30 * MBYTE);
    short* xq_bf = (short*)(ws + 32 * MBYTE);
    short* xk_bf = (short*)(ws + 40 * MBYTE);
    short* xv_bf = (short*)(ws + 48 * MBYTE);
    short* attn_ws = (short*)(ws + 32 * MBYTE);          // aliases xq_bf (dead after qkv gemm)
    unsigned* mbits = (unsigned*)(ws + 40 * MBYTE);      // aliases xk_bf (dead after qkv gemm)

    cvt_w4_kernel<<<dim3(1024, 4), 256, 0, stream>>>(Wq, Wk, Wv, Wo, wq_bf, wk_bf, wv_bf, wo_bf);
    cvt_x3_kernel<<<dim3(4096, 3), 256, 0, stream>>>(x_q, x_k, x_v, xq_bf, xk_bf, xv_bf);

    dim3 qkvgrid(D_MODELX / 128, M_TOK / 128, 3);
    gemm_qkv_kernel<<<qkvgrid, 256, 0, stream>>>(xq_bf, xk_bf, xv_bf, wq_bf, wk_bf, wv_bf,
                                                 bq, bk, bv, q_ws, k_ws, vT_ws, QSCALE);

    mask_bits_kernel<<<(BBX * SSX * SSX) / 256, 256, 0, stream>>>(mask, mbits);

    attn_kernel<<<BBX * NUM_HEADX * (SSX / 64), 256, 0, stream>>>(q_ws, k_ws, vT_ws, mbits, attn_ws);

    gemm_one_kernel<<<ggrid, 256, 0, stream>>>(attn_ws, wo_bf, bo, 1.0f, d_out, 1);
  } else {
    // sequential low-footprint path (35 MB)
    unsigned* mbits = (unsigned*)(ws + 24 * MBYTE);
    short* w_bf = (short*)(ws + 25 * MBYTE);
    short* x_bf = (short*)(ws + 27 * MBYTE);
    short* attn_ws = (short*)(ws + 27 * MBYTE);  // aliases x_bf

    mask_bits_kernel<<<(BBX * SSX * SSX) / 256, 256, 0, stream>>>(mask, mbits);

    cvt_w4_kernel<<<dim3(1024, 1), 256, 0, stream>>>(Wq, Wq, Wq, Wq, w_bf, w_bf, w_bf, w_bf);
    cvt_x3_kernel<<<dim3(4096, 1), 256, 0, stream>>>(x_q, x_q, x_q, x_bf, x_bf, x_bf);
    gemm_one_kernel<<<ggrid, 256, 0, stream>>>(x_bf, w_bf, bq, QSCALE, q_ws, 0);

    cvt_w4_kernel<<<dim3(1024, 1), 256, 0, stream>>>(Wk, Wk, Wk, Wk, w_bf, w_bf, w_bf, w_bf);
    cvt_x3_kernel<<<dim3(4096, 1), 256, 0, stream>>>(x_k, x_k, x_k, x_bf, x_bf, x_bf);
    gemm_one_kernel<<<ggrid, 256, 0, stream>>>(x_bf, w_bf, bk, 1.0f, k_ws, 0);

    cvt_w4_kernel<<<dim3(1024, 1), 256, 0, stream>>>(Wv, Wv, Wv, Wv, w_bf, w_bf, w_bf, w_bf);
    cvt_x3_kernel<<<dim3(4096, 1), 256, 0, stream>>>(x_v, x_v, x_v, x_bf, x_bf, x_bf);
    gemm_one_kernel<<<ggrid, 256, 0, stream>>>(x_bf, w_bf, bv, 1.0f, vT_ws, 2);

    attn_kernel<<<BBX * NUM_HEADX * (SSX / 64), 256, 0, stream>>>(q_ws, k_ws, vT_ws, mbits, attn_ws);

    cvt_w4_kernel<<<dim3(1024, 1), 256, 0, stream>>>(Wo, Wo, Wo, Wo, w_bf, w_bf, w_bf, w_bf);
    gemm_one_kernel<<<ggrid, 256, 0, stream>>>(attn_ws, w_bf, bo, 1.0f, d_out, 1);
  }
}

// Round 6
// 168.597 us; speedup vs baseline: 4.1765x; 1.0250x over previous
//
#include <hip/hip_runtime.h>
#include <cstdint>
#include <cstddef>

#define D_MODELX 1024
#define NUM_HEADX 16
#define D_KX 64
#define BBX 2
#define SSX 2048
#define M_TOK 4096   // B*S
#define MBYTE (1u << 20)

typedef __attribute__((ext_vector_type(8))) short short8;
typedef __attribute__((ext_vector_type(4))) short short4v;
typedef __attribute__((ext_vector_type(4))) float float4v;

__device__ __forceinline__ short f2bf(float f) {
  unsigned u = __builtin_bit_cast(unsigned, f);
  u = u + 0x7FFFu + ((u >> 16) & 1u);   // RNE
  return (short)(u >> 16);
}

// ---------------- mask -> bitmask ----------------
__global__ void mask_bits_kernel(const int* __restrict__ mask, unsigned* __restrict__ mbits) {
  int i = blockIdx.x * blockDim.x + threadIdx.x;   // over B*S*S = 8388608
  bool v = mask[i] != 0;
  unsigned long long bal = __ballot(v);
  int lane = threadIdx.x & 63;
  if (lane == 0)       mbits[i >> 5] = (unsigned)bal;
  else if (lane == 32) mbits[i >> 5] = (unsigned)(bal >> 32);
}

// ---------------- fp32 -> bf16 converts (merged) ----------------
__global__ void cvt_w4_kernel(const float* __restrict__ w0, const float* __restrict__ w1,
                              const float* __restrict__ w2, const float* __restrict__ w3,
                              short* __restrict__ o0, short* __restrict__ o1,
                              short* __restrict__ o2, short* __restrict__ o3) {
  int z = blockIdx.y;
  const float* in = (z == 0) ? w0 : (z == 1) ? w1 : (z == 2) ? w2 : w3;
  short* out = (z == 0) ? o0 : (z == 1) ? o1 : (z == 2) ? o2 : o3;
  int i = blockIdx.x * blockDim.x + threadIdx.x;   // 1024*256 = 256K = exact
  float4v v = ((const float4v*)in)[i];
  short4v s;
  s[0] = f2bf(v[0]); s[1] = f2bf(v[1]); s[2] = f2bf(v[2]); s[3] = f2bf(v[3]);
  ((short4v*)out)[i] = s;
}

__global__ void cvt_x3_kernel(const float* __restrict__ x0, const float* __restrict__ x1,
                              const float* __restrict__ x2,
                              short* __restrict__ o0, short* __restrict__ o1,
                              short* __restrict__ o2) {
  int z = blockIdx.y;
  const float* in = (z == 0) ? x0 : (z == 1) ? x1 : x2;
  short* out = (z == 0) ? o0 : (z == 1) ? o1 : o2;
  int i = blockIdx.x * blockDim.x + threadIdx.x;   // 4096*256 = 1M = exact
  float4v v = ((const float4v*)in)[i];
  short4v s;
  s[0] = f2bf(v[0]); s[1] = f2bf(v[1]); s[2] = f2bf(v[2]); s[3] = f2bf(v[3]);
  ((short4v*)out)[i] = s;
}

// ---------------- GEMM body: out = (A @ W^T + b) * oscale ----------------
// A: [4096,1024] bf16, W: [1024,1024] bf16 row-major (row = out col)
// Staging via global_load_lds width=16 (linear LDS dest, inverse-swizzled global src,
// swizzled ds_read). Tile 128x128, BK=64, LDS 2x16KB linear [128][64].
#define GBK 64

__device__ __forceinline__ int swbg(int row, int colB) {  // byte offset in [128][64]-short tile
  return row * 128 + (colB ^ ((row & 7) << 4));
}

__device__ __forceinline__ void gemm_body(const short* __restrict__ A,
                                          const short* __restrict__ Bw,
                                          const float* __restrict__ bias,
                                          float oscale, void* __restrict__ outp, int mode) {
  __shared__ short lds_a[128 * 64];
  __shared__ short lds_b[128 * 64];
  const int tid = threadIdx.x;
  const int lane = tid & 63;
  const int wid = tid >> 6;
  const int wm = wid >> 1, wn = wid & 1;
  const int bn = blockIdx.x, bm = blockIdx.y;
  const int l15 = lane & 15, lg = lane >> 4;

  // staging geometry: slot = it*256 + tid (16B slots); row = slot>>3, linear colB = (slot&7)*16
  // global source column pre-swizzled so that swizzled ds_read sees A[row][colB].
  const int s_row = tid >> 3;                 // rows 0..31 per it-step of 32
  const int s_cB = ((tid & 7) << 4) ^ ((s_row & 7) << 4);
  const short* Abase = A + (size_t)(bm * 128) * 1024 + (s_cB >> 1);
  const short* Bbase = Bw + (size_t)(bn * 128) * 1024 + (s_cB >> 1);

  float4v acc[4][4];
#pragma unroll
  for (int m = 0; m < 4; ++m)
#pragma unroll
    for (int n = 0; n < 4; ++n) acc[m][n] = (float4v){0.f, 0.f, 0.f, 0.f};

  for (int kt = 0; kt < 1024; kt += GBK) {
#pragma unroll
    for (int it = 0; it < 4; ++it) {
      int row = it * 32 + s_row;
      __builtin_amdgcn_global_load_lds(
          (const uint32_t*)(Abase + (size_t)row * 1024 + kt),
          (uint32_t*)(lds_a + (it * 256 + wid * 64) * 8), 16, 0, 0);
      __builtin_amdgcn_global_load_lds(
          (const uint32_t*)(Bbase + (size_t)row * 1024 + kt),
          (uint32_t*)(lds_b + (it * 256 + wid * 64) * 8), 16, 0, 0);
    }
    __syncthreads();   // drains vmcnt + lgkm

    short8 af[4][2];
#pragma unroll
    for (int m = 0; m < 4; ++m) {
      int row = wm * 64 + m * 16 + l15;
      af[m][0] = *(const short8*)((const char*)lds_a + swbg(row, lg * 16));
      af[m][1] = *(const short8*)((const char*)lds_a + swbg(row, 64 + lg * 16));
    }
#pragma unroll
    for (int n = 0; n < 4; ++n) {
      int rowb = wn * 64 + n * 16 + l15;
      short8 b0 = *(const short8*)((const char*)lds_b + swbg(rowb, lg * 16));
      short8 b1 = *(const short8*)((const char*)lds_b + swbg(rowb, 64 + lg * 16));
#pragma unroll
      for (int m = 0; m < 4; ++m) {
        acc[m][n] = __builtin_amdgcn_mfma_f32_16x16x32_bf16(af[m][0], b0, acc[m][n], 0, 0, 0);
        acc[m][n] = __builtin_amdgcn_mfma_f32_16x16x32_bf16(af[m][1], b1, acc[m][n], 0, 0, 0);
      }
    }
    __syncthreads();
  }

#pragma unroll
  for (int n = 0; n < 4; ++n) {
    int col = bn * 128 + wn * 64 + n * 16 + l15;
    float bv = bias[col];
#pragma unroll
    for (int m = 0; m < 4; ++m) {
      if (mode == 2) {
        int base_row = bm * 128 + wm * 64 + m * 16 + lg * 4;
        int bidx = base_row >> 11, s = base_row & 2047;
        int h = col >> 6, d = col & 63;
        short4v sv;
#pragma unroll
        for (int r = 0; r < 4; ++r) sv[r] = f2bf(acc[m][n][r] + bv);
        *(short4v*)&((short*)outp)[(((size_t)(bidx * NUM_HEADX + h)) * D_KX + d) * SSX + s] = sv;
      } else {
#pragma unroll
        for (int r = 0; r < 4; ++r) {
          int row = bm * 128 + wm * 64 + m * 16 + lg * 4 + r;
          float val = (acc[m][n][r] + bv) * oscale;
          if (mode == 0) {
            int bidx = row >> 11, s = row & 2047;
            int h = col >> 6, d = col & 63;
            ((short*)outp)[(((size_t)(bidx * NUM_HEADX + h)) * SSX + s) * D_KX + d] = f2bf(val);
          } else {
            ((float*)outp)[(size_t)row * D_MODELX + col] = val;
          }
        }
      }
    }
  }
}

__global__ __launch_bounds__(256) void gemm_qkv_kernel(
    const short* __restrict__ xq, const short* __restrict__ xk, const short* __restrict__ xv,
    const short* __restrict__ wq, const short* __restrict__ wk, const short* __restrict__ wv,
    const float* __restrict__ bq, const float* __restrict__ bk, const float* __restrict__ bv,
    short* __restrict__ qo, short* __restrict__ ko, short* __restrict__ vo, float qs) {
  int z = blockIdx.z;
  const short* A = (z == 0) ? xq : (z == 1) ? xk : xv;
  const short* W = (z == 0) ? wq : (z == 1) ? wk : wv;
  const float* bi = (z == 0) ? bq : (z == 1) ? bk : bv;
  void* out = (z == 0) ? (void*)qo : (z == 1) ? (void*)ko : (void*)vo;
  float os = (z == 0) ? qs : 1.0f;
  int mode = (z == 2) ? 2 : 0;
  gemm_body(A, W, bi, os, out, mode);
}

__global__ __launch_bounds__(256) void gemm_one_kernel(const short* __restrict__ A,
                                                       const short* __restrict__ W,
                                                       const float* __restrict__ bias,
                                                       float os, void* __restrict__ out, int mode) {
  gemm_body(A, W, bias, os, out, mode);
}

// ---------------- flash attention (swapped-operand, scalar-per-lane softmax) ----------------
// grid: (B*H)*(S/64) blocks, 256 threads (4 waves). 16 q-rows/wave (q = l15), KVBLK=64.
// S^T = mfma(K_frag, Q_frag): lane holds scores for q=l15, k = kf*16 + lg*4 + r.
// O^T = mfma(V^T_frag, P_frag): acc[db][r] = O[q=l15][d = db*16 + lg*4 + r].
// __launch_bounds__(256,4): LDS caps at 4 blocks/CU anyway; VGPR cap 128 keeps the
// ~28 loop-invariant swizzled LDS addresses hoisted (VGPR=64 forced rematerialization).
__device__ __forceinline__ int swzk(int row, int col) {  // rows of 64 shorts (128B)
  int byte = (row << 7) + (col << 1);
  return (byte ^ ((row & 7) << 4)) >> 1;
}

__global__ __launch_bounds__(256, 4) void attn_kernel(const short* __restrict__ q_ws,
                                                      const short* __restrict__ k_ws,
                                                      const short* __restrict__ vT_ws,
                                                      const unsigned* __restrict__ mbits,
                                                      short* __restrict__ attn_ws) {
  __shared__ short k_lds[2][64 * 64];
  __shared__ short vT_lds[2][64 * 64];
  __shared__ short p_lds[4][16 * 64];

  const int tid = threadIdx.x;
  const int lane = tid & 63;
  const int w = tid >> 6;
  const int l15 = lane & 15, lg = lane >> 4;
  // XCD-aware bijective swizzle: 1024 blocks = 8 XCDs x 128; each XCD owns 4 heads
  const int bid0 = blockIdx.x;
  const int bid = ((bid0 & 7) << 7) | (bid0 >> 3);
  const int qt = bid & 31;
  const int bh = bid >> 5;
  const int b = bh >> 4;
  const int h = bh & 15;

  short* pw = p_lds[w];
  const int qrow = qt * 64 + w * 16;

  const int srow = tid >> 2;
  const int scol = (tid & 3) << 4;
  const short* Kb = k_ws + (size_t)bh * SSX * D_KX;
  const short* Vb = vT_ws + (size_t)bh * D_KX * SSX;

  // Q fragment (B-operand): lane holds Q[q=l15][d = c*32 + lg*8 + j]
  short8 qf[2];
#pragma unroll
  for (int f = 0; f < 2; ++f)
    qf[f] = *(const short8*)(q_ws + ((size_t)bh * SSX + qrow + l15) * D_KX + f * 32 + lg * 8);

  float4v acc[4];
#pragma unroll
  for (int db = 0; db < 4; ++db) acc[db] = (float4v){0.f, 0.f, 0.f, 0.f};
  float m_run = -INFINITY, l_part = 0.f;

  short8 kr0, kr1, vr0, vr1;
  auto loadt = [&](int kb) {
    const short* kp = Kb + (size_t)(kb + srow) * D_KX + scol;
    kr0 = *(const short8*)kp;
    kr1 = *(const short8*)(kp + 8);
    const short* vp = Vb + (size_t)srow * SSX + kb + scol;
    vr0 = *(const short8*)vp;
    vr1 = *(const short8*)(vp + 8);
  };
  auto storet = [&](int bf) {
    *(short8*)&k_lds[bf][swzk(srow, scol)] = kr0;
    *(short8*)&k_lds[bf][swzk(srow, scol + 8)] = kr1;
    *(short8*)&vT_lds[bf][swzk(srow, scol)] = vr0;
    *(short8*)&vT_lds[bf][swzk(srow, scol + 8)] = vr1;
  };

  // one mask word per lane: q-row = qrow + l15
  const unsigned* mrow = mbits + ((size_t)b * SSX + qrow + l15) * (SSX / 32);
  unsigned long long mw = *(const unsigned long long*)mrow, mwn;

  loadt(0);
  storet(0);
  loadt(64);
  __syncthreads();

  for (int t = 0; t < 32; ++t) {
    const int cur = t & 1;
    const short* kl = k_lds[cur];
    const short* vl = vT_lds[cur];

    // S^T = K * Q^T: p[kf][r] = score(q=l15, k = kf*16 + lg*4 + r), log2-domain
    float p[4][4];
#pragma unroll
    for (int kf = 0; kf < 4; ++kf) {
      short8 k0 = *(const short8*)&kl[swzk(kf * 16 + l15, lg * 8)];
      short8 k1 = *(const short8*)&kl[swzk(kf * 16 + l15, 32 + lg * 8)];
      float4v f = (float4v){0.f, 0.f, 0.f, 0.f};
      f = __builtin_amdgcn_mfma_f32_16x16x32_bf16(k0, qf[0], f, 0, 0, 0);
      f = __builtin_amdgcn_mfma_f32_16x16x32_bf16(k1, qf[1], f, 0, 0, 0);
#pragma unroll
      for (int r = 0; r < 4; ++r) p[kf][r] = f[r];
    }

    // early staging + mask prefetch: hide global latency under softmax+PV
    if (t < 31) storet(1 - cur);
    if (t < 30) loadt((t + 2) * 64);
    if (t < 31) mwn = *(const unsigned long long*)(mrow + 2 * (t + 1));

    // per-lane raw tile max (q=l15 fully lane-local); defer-max THR=8 (log2)
    float tmax = fmaxf(fmaxf(fmaxf(p[0][0], p[0][1]), fmaxf(p[0][2], p[0][3])),
                       fmaxf(fmaxf(p[1][0], p[1][1]), fmaxf(p[1][2], p[1][3])));
    tmax = fmaxf(tmax, fmaxf(fmaxf(fmaxf(p[2][0], p[2][1]), fmaxf(p[2][2], p[2][3])),
                             fmaxf(fmaxf(p[3][0], p[3][1]), fmaxf(p[3][2], p[3][3]))));
    if (!__all(tmax - m_run <= 8.0f)) {
      // full path: reduce max across the 4 lg-groups holding this q-row
      tmax = fmaxf(tmax, __shfl_xor(tmax, 16));
      tmax = fmaxf(tmax, __shfl_xor(tmax, 32));
      float mn = fmaxf(m_run, tmax);
      float corr = __builtin_amdgcn_exp2f(m_run - mn);
      m_run = mn;
      l_part *= corr;
#pragma unroll
      for (int db = 0; db < 4; ++db)
#pragma unroll
        for (int r = 0; r < 4; ++r) acc[db][r] *= corr;
    }

    // mask bits for this lane's 16 k's: bit (kf*16 + r) of (mw >> lg*4)
    unsigned long long sh = mw >> (lg * 4);
    unsigned mlo = (unsigned)sh, mhi = (unsigned)(sh >> 32);

    // exp2, mask-zero, lazy-l, pack to bf16 pairs, write P row q=l15
#pragma unroll
    for (int kf = 0; kf < 4; ++kf) {
      float pv_[4];
#pragma unroll
      for (int r = 0; r < 4; ++r) {
        float pv = __builtin_amdgcn_exp2f(p[kf][r] - m_run);
        unsigned bit = (kf < 2 ? mlo : mhi) & (1u << ((kf & 1) * 16 + r));
        pv = bit ? pv : 0.0f;
        l_part += pv;
        pv_[r] = pv;
      }
      unsigned u0, u1;
      asm("v_cvt_pk_bf16_f32 %0, %1, %2" : "=v"(u0) : "v"(pv_[0]), "v"(pv_[1]));
      asm("v_cvt_pk_bf16_f32 %0, %1, %2" : "=v"(u1) : "v"(pv_[2]), "v"(pv_[3]));
      uint2 w2;
      w2.x = u0; w2.y = u1;
      *(uint2*)&pw[swzk(l15, kf * 16 + lg * 4)] = w2;
    }

    // O^T += V^T * P^T: acc[db][r] = O[q=l15][d=db*16+lg*4+r]
#pragma unroll
    for (int db = 0; db < 4; ++db) {
#pragma unroll
      for (int c = 0; c < 2; ++c) {
        short8 vb = *(const short8*)&vl[swzk(db * 16 + l15, c * 32 + lg * 8)];
        short8 pa = *(const short8*)&pw[swzk(l15, c * 32 + lg * 8)];
        acc[db] = __builtin_amdgcn_mfma_f32_16x16x32_bf16(vb, pa, acc[db], 0, 0, 0);
      }
    }

    __syncthreads();
    mw = mwn;
  }

  // final l reduction across the 4 lg-groups + epilogue (4 consecutive d per db)
  l_part += __shfl_xor(l_part, 16);
  l_part += __shfl_xor(l_part, 32);
  float inv = 1.0f / l_part;

  size_t ttok = (size_t)b * SSX + qrow + l15;
#pragma unroll
  for (int db = 0; db < 4; ++db) {
    short4v sv;
#pragma unroll
    for (int r = 0; r < 4; ++r) sv[r] = f2bf(acc[db][r] * inv);
    *(short4v*)&attn_ws[ttok * D_MODELX + h * 64 + db * 16 + lg * 4] = sv;
  }
}

// ---------------- launcher ----------------
extern "C" void kernel_launch(void* const* d_in, const int* in_sizes, int n_in,
                              void* d_out, int out_size, void* d_ws, size_t ws_size,
                              hipStream_t stream) {
  const float* x_q = (const float*)d_in[0];
  const float* x_k = (const float*)d_in[1];
  const float* x_v = (const float*)d_in[2];
  const int*   mask = (const int*)d_in[3];
  const float* Wq = (const float*)d_in[4];
  const float* bq = (const float*)d_in[5];
  const float* Wk = (const float*)d_in[6];
  const float* bk = (const float*)d_in[7];
  const float* Wv = (const float*)d_in[8];
  const float* bv = (const float*)d_in[9];
  const float* Wo = (const float*)d_in[10];
  const float* bo = (const float*)d_in[11];

  const float QSCALE = 0.125f * 1.44269504089f;

  char* ws = (char*)d_ws;
  short* q_ws  = (short*)(ws + 0 * MBYTE);
  short* k_ws  = (short*)(ws + 8 * MBYTE);
  short* vT_ws = (short*)(ws + 16 * MBYTE);

  dim3 ggrid(D_MODELX / 128, M_TOK / 128);

  if (ws_size >= (size_t)56 * MBYTE) {
    short* wq_bf = (short*)(ws + 24 * MBYTE);
    short* wk_bf = (short*)(ws + 26 * MBYTE);
    short* wv_bf = (short*)(ws + 28 * MBYTE);
    short* wo_bf = (short*)(ws + 30 * MBYTE);
    short* xq_bf = (short*)(ws + 32 * MBYTE);
    short* xk_bf = (short*)(ws + 40 * MBYTE);
    short* xv_bf = (short*)(ws + 48 * MBYTE);
    short* attn_ws = (short*)(ws + 32 * MBYTE);          // aliases xq_bf (dead after qkv gemm)
    unsigned* mbits = (unsigned*)(ws + 40 * MBYTE);      // aliases xk_bf (dead after qkv gemm)

    cvt_w4_kernel<<<dim3(1024, 4), 256, 0, stream>>>(Wq, Wk, Wv, Wo, wq_bf, wk_bf, wv_bf, wo_bf);
    cvt_x3_kernel<<<dim3(4096, 3), 256, 0, stream>>>(x_q, x_k, x_v, xq_bf, xk_bf, xv_bf);

    dim3 qkvgrid(D_MODELX / 128, M_TOK / 128, 3);
    gemm_qkv_kernel<<<qkvgrid, 256, 0, stream>>>(xq_bf, xk_bf, xv_bf, wq_bf, wk_bf, wv_bf,
                                                 bq, bk, bv, q_ws, k_ws, vT_ws, QSCALE);

    mask_bits_kernel<<<(BBX * SSX * SSX) / 256, 256, 0, stream>>>(mask, mbits);

    attn_kernel<<<BBX * NUM_HEADX * (SSX / 64), 256, 0, stream>>>(q_ws, k_ws, vT_ws, mbits, attn_ws);

    gemm_one_kernel<<<ggrid, 256, 0, stream>>>(attn_ws, wo_bf, bo, 1.0f, d_out, 1);
  } else {
    // sequential low-footprint path (35 MB)
    unsigned* mbits = (unsigned*)(ws + 24 * MBYTE);
    short* w_bf = (short*)(ws + 25 * MBYTE);
    short* x_bf = (short*)(ws + 27 * MBYTE);
    short* attn_ws = (short*)(ws + 27 * MBYTE);  // aliases x_bf

    mask_bits_kernel<<<(BBX * SSX * SSX) / 256, 256, 0, stream>>>(mask, mbits);

    cvt_w4_kernel<<<dim3(1024, 1), 256, 0, stream>>>(Wq, Wq, Wq, Wq, w_bf, w_bf, w_bf, w_bf);
    cvt_x3_kernel<<<dim3(4096, 1), 256, 0, stream>>>(x_q, x_q, x_q, x_bf, x_bf, x_bf);
    gemm_one_kernel<<<ggrid, 256, 0, stream>>>(x_bf, w_bf, bq, QSCALE, q_ws, 0);

    cvt_w4_kernel<<<dim3(1024, 1), 256, 0, stream>>>(Wk, Wk, Wk, Wk, w_bf, w_bf, w_bf, w_bf);
    cvt_x3_kernel<<<dim3(4096, 1), 256, 0, stream>>>(x_k, x_k, x_k, x_bf, x_bf, x_bf);
    gemm_one_kernel<<<ggrid, 256, 0, stream>>>(x_bf, w_bf, bk, 1.0f, k_ws, 0);

    cvt_w4_kernel<<<dim3(1024, 1), 256, 0, stream>>>(Wv, Wv, Wv, Wv, w_bf, w_bf, w_bf, w_bf);
    cvt_x3_kernel<<<dim3(4096, 1), 256, 0, stream>>>(x_v, x_v, x_v, x_bf, x_bf, x_bf);
    gemm_one_kernel<<<ggrid, 256, 0, stream>>>(x_bf, w_bf, bv, 1.0f, vT_ws, 2);

    attn_kernel<<<BBX * NUM_HEADX * (SSX / 64), 256, 0, stream>>>(q_ws, k_ws, vT_ws, mbits, attn_ws);

    cvt_w4_kernel<<<dim3(1024, 1), 256, 0, stream>>>(Wo, Wo, Wo, Wo, w_bf, w_bf, w_bf, w_bf);
    gemm_one_kernel<<<ggrid, 256, 0, stream>>>(attn_ws, w_bf, bo, 1.0f, d_out, 1);
  }
}

// Round 8
// 167.594 us; speedup vs baseline: 4.2015x; 1.0060x over previous
//
#include <hip/hip_runtime.h>
#include <cstdint>
#include <cstddef>

#define D_MODELX 1024
#define NUM_HEADX 16
#define D_KX 64
#define BBX 2
#define SSX 2048
#define M_TOK 4096   // B*S
#define MBYTE (1u << 20)

typedef __attribute__((ext_vector_type(8))) short short8;
typedef __attribute__((ext_vector_type(4))) short short4v;
typedef __attribute__((ext_vector_type(4))) float float4v;

__device__ __forceinline__ short f2bf(float f) {
  unsigned u = __builtin_bit_cast(unsigned, f);
  u = u + 0x7FFFu + ((u >> 16) & 1u);   // RNE
  return (short)(u >> 16);
}

// ---------------- mask -> bitmask ----------------
__global__ void mask_bits_kernel(const int* __restrict__ mask, unsigned* __restrict__ mbits) {
  int i = blockIdx.x * blockDim.x + threadIdx.x;   // over B*S*S = 8388608
  bool v = mask[i] != 0;
  unsigned long long bal = __ballot(v);
  int lane = threadIdx.x & 63;
  if (lane == 0)       mbits[i >> 5] = (unsigned)bal;
  else if (lane == 32) mbits[i >> 5] = (unsigned)(bal >> 32);
}

// ---------------- fp32 -> bf16 converts (merged) ----------------
__global__ void cvt_w4_kernel(const float* __restrict__ w0, const float* __restrict__ w1,
                              const float* __restrict__ w2, const float* __restrict__ w3,
                              short* __restrict__ o0, short* __restrict__ o1,
                              short* __restrict__ o2, short* __restrict__ o3) {
  int z = blockIdx.y;
  const float* in = (z == 0) ? w0 : (z == 1) ? w1 : (z == 2) ? w2 : w3;
  short* out = (z == 0) ? o0 : (z == 1) ? o1 : (z == 2) ? o2 : o3;
  int i = blockIdx.x * blockDim.x + threadIdx.x;   // 1024*256 = 256K = exact
  float4v v = ((const float4v*)in)[i];
  short4v s;
  s[0] = f2bf(v[0]); s[1] = f2bf(v[1]); s[2] = f2bf(v[2]); s[3] = f2bf(v[3]);
  ((short4v*)out)[i] = s;
}

__global__ void cvt_x3_kernel(const float* __restrict__ x0, const float* __restrict__ x1,
                              const float* __restrict__ x2,
                              short* __restrict__ o0, short* __restrict__ o1,
                              short* __restrict__ o2) {
  int z = blockIdx.y;
  const float* in = (z == 0) ? x0 : (z == 1) ? x1 : x2;
  short* out = (z == 0) ? o0 : (z == 1) ? o1 : o2;
  int i = blockIdx.x * blockDim.x + threadIdx.x;   // 4096*256 = 1M = exact
  float4v v = ((const float4v*)in)[i];
  short4v s;
  s[0] = f2bf(v[0]); s[1] = f2bf(v[1]); s[2] = f2bf(v[2]); s[3] = f2bf(v[3]);
  ((short4v*)out)[i] = s;
}

// ---------------- GEMM body: out = (A @ W^T + b) * oscale ----------------
// Staging via global_load_lds width=16 (linear LDS dest, inverse-swizzled global src).
// All fragment ds_reads are per-lane-base + compile-time immediate (m -> +2048B).
#define GBK 64

__device__ __forceinline__ void gemm_body(const short* __restrict__ A,
                                          const short* __restrict__ Bw,
                                          const float* __restrict__ bias,
                                          float oscale, void* __restrict__ outp, int mode) {
  __shared__ short lds_a[128 * 64];
  __shared__ short lds_b[128 * 64];
  const int tid = threadIdx.x;
  const int lane = tid & 63;
  const int wid = tid >> 6;
  const int wm = wid >> 1, wn = wid & 1;
  const int bn = blockIdx.x, bm = blockIdx.y;
  const int l15 = lane & 15, lg = lane >> 4;

  // staging geometry: slot = it*256 + tid; dest linear; global col pre-swizzled
  const int s_row = tid >> 3;
  const int s_cB = ((tid & 7) << 4) ^ ((s_row & 7) << 4);
  const short* Abase = A + (size_t)(bm * 128) * 1024 + (s_cB >> 1);
  const short* Bbase = Bw + (size_t)(bn * 128) * 1024 + (s_cB >> 1);

  // fragment read bases (bytes): row = (w?*64 + l15) + m*16; row&7 == l15&7
  const int xmask = (l15 & 7) << 4;
  const int a_b0 = (wm * 64 + l15) * 128 + ((lg * 16) ^ xmask);
  const int a_b1 = (wm * 64 + l15) * 128 + ((64 + lg * 16) ^ xmask);
  const int b_b0 = (wn * 64 + l15) * 128 + ((lg * 16) ^ xmask);
  const int b_b1 = (wn * 64 + l15) * 128 + ((64 + lg * 16) ^ xmask);

  float4v acc[4][4];
#pragma unroll
  for (int m = 0; m < 4; ++m)
#pragma unroll
    for (int n = 0; n < 4; ++n) acc[m][n] = (float4v){0.f, 0.f, 0.f, 0.f};

  for (int kt = 0; kt < 1024; kt += GBK) {
#pragma unroll
    for (int it = 0; it < 4; ++it) {
      int row = it * 32 + s_row;
      __builtin_amdgcn_global_load_lds(
          (const uint32_t*)(Abase + (size_t)row * 1024 + kt),
          (uint32_t*)(lds_a + (it * 256 + wid * 64) * 8), 16, 0, 0);
      __builtin_amdgcn_global_load_lds(
          (const uint32_t*)(Bbase + (size_t)row * 1024 + kt),
          (uint32_t*)(lds_b + (it * 256 + wid * 64) * 8), 16, 0, 0);
    }
    __syncthreads();   // drains vmcnt + lgkm

    short8 af[4][2];
#pragma unroll
    for (int m = 0; m < 4; ++m) {
      af[m][0] = *(const short8*)((const char*)lds_a + a_b0 + m * 2048);
      af[m][1] = *(const short8*)((const char*)lds_a + a_b1 + m * 2048);
    }
#pragma unroll
    for (int n = 0; n < 4; ++n) {
      short8 b0 = *(const short8*)((const char*)lds_b + b_b0 + n * 2048);
      short8 b1 = *(const short8*)((const char*)lds_b + b_b1 + n * 2048);
#pragma unroll
      for (int m = 0; m < 4; ++m) {
        acc[m][n] = __builtin_amdgcn_mfma_f32_16x16x32_bf16(af[m][0], b0, acc[m][n], 0, 0, 0);
        acc[m][n] = __builtin_amdgcn_mfma_f32_16x16x32_bf16(af[m][1], b1, acc[m][n], 0, 0, 0);
      }
    }
    __syncthreads();
  }

#pragma unroll
  for (int n = 0; n < 4; ++n) {
    int col = bn * 128 + wn * 64 + n * 16 + l15;
    float bv = bias[col];
#pragma unroll
    for (int m = 0; m < 4; ++m) {
      if (mode == 2) {
        int base_row = bm * 128 + wm * 64 + m * 16 + lg * 4;
        int bidx = base_row >> 11, s = base_row & 2047;
        int h = col >> 6, d = col & 63;
        short4v sv;
#pragma unroll
        for (int r = 0; r < 4; ++r) sv[r] = f2bf(acc[m][n][r] + bv);
        *(short4v*)&((short*)outp)[(((size_t)(bidx * NUM_HEADX + h)) * D_KX + d) * SSX + s] = sv;
      } else {
#pragma unroll
        for (int r = 0; r < 4; ++r) {
          int row = bm * 128 + wm * 64 + m * 16 + lg * 4 + r;
          float val = (acc[m][n][r] + bv) * oscale;
          if (mode == 0) {
            int bidx = row >> 11, s = row & 2047;
            int h = col >> 6, d = col & 63;
            ((short*)outp)[(((size_t)(bidx * NUM_HEADX + h)) * SSX + s) * D_KX + d] = f2bf(val);
          } else {
            ((float*)outp)[(size_t)row * D_MODELX + col] = val;
          }
        }
      }
    }
  }
}

__global__ __launch_bounds__(256) void gemm_qkv_kernel(
    const short* __restrict__ xq, const short* __restrict__ xk, const short* __restrict__ xv,
    const short* __restrict__ wq, const short* __restrict__ wk, const short* __restrict__ wv,
    const float* __restrict__ bq, const float* __restrict__ bk, const float* __restrict__ bv,
    short* __restrict__ qo, short* __restrict__ ko, short* __restrict__ vo, float qs) {
  int z = blockIdx.z;
  const short* A = (z == 0) ? xq : (z == 1) ? xk : xv;
  const short* W = (z == 0) ? wq : (z == 1) ? wk : wv;
  const float* bi = (z == 0) ? bq : (z == 1) ? bk : bv;
  void* out = (z == 0) ? (void*)qo : (z == 1) ? (void*)ko : (void*)vo;
  float os = (z == 0) ? qs : 1.0f;
  int mode = (z == 2) ? 2 : 0;
  gemm_body(A, W, bi, os, out, mode);
}

__global__ __launch_bounds__(256) void gemm_one_kernel(const short* __restrict__ A,
                                                       const short* __restrict__ W,
                                                       const float* __restrict__ bias,
                                                       float os, void* __restrict__ out, int mode) {
  gemm_body(A, W, bias, os, out, mode);
}

// ---------------- flash attention (swapped-operand; base+immediate LDS addressing) ----------------
// grid: (B*H)*(S/64) blocks, 256 threads (4 waves). 16 q-rows/wave (q = l15), KVBLK=64.
// S^T = mfma(K, Q): lane holds scores for q=l15, k = kf*16 + lg*4 + r.
// O^T = mfma(V^T, P^T): acc[db][r] = O[q=l15][d = db*16 + lg*4 + r].
// All in-loop DS ops use per-lane bases + literal immediates (kf/db -> +2048B, buffer -> +8192B
// via unroll-2 with literal buffer offsets). P stored chunked [kf][q=l15][k'16] -> conflict-free.
__global__ __launch_bounds__(256, 4) void attn_kernel(const short* __restrict__ q_ws,
                                                      const short* __restrict__ k_ws,
                                                      const short* __restrict__ vT_ws,
                                                      const unsigned* __restrict__ mbits,
                                                      short* __restrict__ attn_ws) {
  __shared__ short k_lds[2][64 * 64];    // [ki][d] swizzled, 8192B per buf
  __shared__ short vT_lds[2][64 * 64];   // [d][ki] swizzled
  __shared__ short p_lds[4][1024];       // per-wave [kf][q=l15][k'16] chunks, 2048B

  const int tid = threadIdx.x;
  const int lane = tid & 63;
  const int w = tid >> 6;
  const int l15 = lane & 15, lg = lane >> 4;
  // XCD-aware bijective swizzle: 1024 blocks = 8 XCDs x 128
  const int bid0 = blockIdx.x;
  const int bid = ((bid0 & 7) << 7) | (bid0 >> 3);
  const int qt = bid & 31;
  const int bh = bid >> 5;
  const int b = bh >> 4;
  const int h = bh & 15;

  const int qrow = qt * 64 + w * 16;

  // ---- per-lane LDS byte bases (computed once) ----
  const int xm15 = (l15 & 7) << 4;
  const int rd_c0 = l15 * 128 + ((lg * 16) ^ xm15);        // + kf/db*2048 (+buf)
  const int rd_c1 = l15 * 128 + ((64 + lg * 16) ^ xm15);
  char* kbase = (char*)k_lds;
  char* vbase = (char*)vT_lds;
  char* pwave = (char*)p_lds[w];
  const int pw_off = l15 * 32 + lg * 8;                    // + kf*512
  const int pr_off = (lg >> 1) * 512 + l15 * 32 + (lg & 1) * 16;  // + c*1024

  const int srow = tid >> 2;                // 0..63
  const int scolS = (tid & 3) * 16;         // shorts
  const int st0 = srow * 128 + ((scolS * 2) ^ ((srow & 7) << 4));
  const int st1 = srow * 128 + ((scolS * 2 + 16) ^ ((srow & 7) << 4));   // FIX: +16B (8 shorts), was +32

  const short* kp = k_ws + (size_t)bh * SSX * D_KX + (size_t)srow * D_KX + scolS;
  const short* vp = vT_ws + (size_t)bh * D_KX * SSX + (size_t)srow * SSX + scolS;

  // Q fragment (B-operand): lane holds Q[q=l15][d = f*32 + lg*8 + j]
  short8 qf[2];
#pragma unroll
  for (int f = 0; f < 2; ++f)
    qf[f] = *(const short8*)(q_ws + ((size_t)bh * SSX + qrow + l15) * D_KX + f * 32 + lg * 8);

  float4v acc[4];
#pragma unroll
  for (int db = 0; db < 4; ++db) acc[db] = (float4v){0.f, 0.f, 0.f, 0.f};
  float m_run = -INFINITY, l_part = 0.f;

  short8 kr0, kr1, vr0, vr1;
  auto loadt = [&](int kb) {
    const short* kq = kp + (size_t)kb * D_KX;
    kr0 = *(const short8*)kq;
    kr1 = *(const short8*)(kq + 8);
    const short* vq = vp + kb;
    vr0 = *(const short8*)vq;
    vr1 = *(const short8*)(vq + 8);
  };
  auto storet = [&](int BUF) {
    *(short8*)(kbase + BUF + st0) = kr0;
    *(short8*)(kbase + BUF + st1) = kr1;
    *(short8*)(vbase + BUF + st0) = vr0;
    *(short8*)(vbase + BUF + st1) = vr1;
  };

  // one mask word per lane: q-row = qrow + l15
  const unsigned* mrow = mbits + ((size_t)b * SSX + qrow + l15) * (SSX / 32);
  unsigned long long mw = *(const unsigned long long*)mrow, mwn = 0;

  loadt(0);
  storet(0);
  loadt(64);
  __syncthreads();

  auto step = [&](int t, int CURB, int NXTB) {
    // S^T = K * Q^T (log2-domain via pre-scaled Q)
    float p[4][4];
#pragma unroll
    for (int kf = 0; kf < 4; ++kf) {
      short8 k0 = *(const short8*)(kbase + CURB + rd_c0 + kf * 2048);
      short8 k1 = *(const short8*)(kbase + CURB + rd_c1 + kf * 2048);
      float4v f = (float4v){0.f, 0.f, 0.f, 0.f};
      f = __builtin_amdgcn_mfma_f32_16x16x32_bf16(k0, qf[0], f, 0, 0, 0);
      f = __builtin_amdgcn_mfma_f32_16x16x32_bf16(k1, qf[1], f, 0, 0, 0);
#pragma unroll
      for (int r = 0; r < 4; ++r) p[kf][r] = f[r];
    }

    // early staging + mask prefetch (hide global latency under softmax+PV)
    if (t < 31) storet(NXTB);
    if (t < 30) loadt((t + 2) * 64);
    if (t < 31) mwn = *(const unsigned long long*)(mrow + 2 * (t + 1));

    // per-lane raw tile max; defer-max THR=8 (log2 domain)
    float tmax = fmaxf(fmaxf(fmaxf(p[0][0], p[0][1]), fmaxf(p[0][2], p[0][3])),
                       fmaxf(fmaxf(p[1][0], p[1][1]), fmaxf(p[1][2], p[1][3])));
    tmax = fmaxf(tmax, fmaxf(fmaxf(fmaxf(p[2][0], p[2][1]), fmaxf(p[2][2], p[2][3])),
                             fmaxf(fmaxf(p[3][0], p[3][1]), fmaxf(p[3][2], p[3][3]))));
    if (!__all(tmax - m_run <= 8.0f)) {
      tmax = fmaxf(tmax, __shfl_xor(tmax, 16));
      tmax = fmaxf(tmax, __shfl_xor(tmax, 32));
      float mn = fmaxf(m_run, tmax);
      float corr = __builtin_amdgcn_exp2f(m_run - mn);
      m_run = mn;
      l_part *= corr;
#pragma unroll
      for (int db = 0; db < 4; ++db)
#pragma unroll
        for (int r = 0; r < 4; ++r) acc[db][r] *= corr;
    }

    // mask bits for this lane's 16 k's: bit (kf*16 + r) of (mw >> lg*4)
    unsigned long long sh = mw >> (lg * 4);
    unsigned mlo = (unsigned)sh, mhi = (unsigned)(sh >> 32);

    // exp2, mask-zero, lazy-l (tree), pack bf16, write P chunk (base+imm, conflict-free)
    float tsum = 0.f;
#pragma unroll
    for (int kf = 0; kf < 4; ++kf) {
      float pv_[4];
#pragma unroll
      for (int r = 0; r < 4; ++r) {
        float pv = __builtin_amdgcn_exp2f(p[kf][r] - m_run);
        unsigned bit = (kf < 2 ? mlo : mhi) & (1u << ((kf & 1) * 16 + r));
        pv_[r] = bit ? pv : 0.0f;
      }
      tsum += (pv_[0] + pv_[1]) + (pv_[2] + pv_[3]);
      unsigned u0, u1;
      asm("v_cvt_pk_bf16_f32 %0, %1, %2" : "=v"(u0) : "v"(pv_[0]), "v"(pv_[1]));
      asm("v_cvt_pk_bf16_f32 %0, %1, %2" : "=v"(u1) : "v"(pv_[2]), "v"(pv_[3]));
      uint2 w2;
      w2.x = u0; w2.y = u1;
      *(uint2*)(pwave + pw_off + kf * 512) = w2;
    }
    l_part += tsum;

    // P fragments (hoisted: independent of db)
    short8 pa0 = *(const short8*)(pwave + pr_off);
    short8 pa1 = *(const short8*)(pwave + pr_off + 1024);

    // O^T += V^T * P^T
#pragma unroll
    for (int db = 0; db < 4; ++db) {
      short8 vb0 = *(const short8*)(vbase + CURB + rd_c0 + db * 2048);
      short8 vb1 = *(const short8*)(vbase + CURB + rd_c1 + db * 2048);
      acc[db] = __builtin_amdgcn_mfma_f32_16x16x32_bf16(vb0, pa0, acc[db], 0, 0, 0);
      acc[db] = __builtin_amdgcn_mfma_f32_16x16x32_bf16(vb1, pa1, acc[db], 0, 0, 0);
    }

    __syncthreads();
    mw = mwn;
  };

  for (int t2 = 0; t2 < 16; ++t2) {
    step(2 * t2, 0, 8192);
    step(2 * t2 + 1, 8192, 0);
  }

  // final l reduction across the 4 lg-groups + epilogue
  l_part += __shfl_xor(l_part, 16);
  l_part += __shfl_xor(l_part, 32);
  float inv = 1.0f / l_part;

  size_t ttok = (size_t)b * SSX + qrow + l15;
#pragma unroll
  for (int db = 0; db < 4; ++db) {
    short4v sv;
#pragma unroll
    for (int r = 0; r < 4; ++r) sv[r] = f2bf(acc[db][r] * inv);
    *(short4v*)&attn_ws[ttok * D_MODELX + h * 64 + db * 16 + lg * 4] = sv;
  }
}

// ---------------- launcher ----------------
extern "C" void kernel_launch(void* const* d_in, const int* in_sizes, int n_in,
                              void* d_out, int out_size, void* d_ws, size_t ws_size,
                              hipStream_t stream) {
  const float* x_q = (const float*)d_in[0];
  const float* x_k = (const float*)d_in[1];
  const float* x_v = (const float*)d_in[2];
  const int*   mask = (const int*)d_in[3];
  const float* Wq = (const float*)d_in[4];
  const float* bq = (const float*)d_in[5];
  const float* Wk = (const float*)d_in[6];
  const float* bk = (const float*)d_in[7];
  const float* Wv = (const float*)d_in[8];
  const float* bv = (const float*)d_in[9];
  const float* Wo = (const float*)d_in[10];
  const float* bo = (const float*)d_in[11];

  const float QSCALE = 0.125f * 1.44269504089f;

  char* ws = (char*)d_ws;
  short* q_ws  = (short*)(ws + 0 * MBYTE);
  short* k_ws  = (short*)(ws + 8 * MBYTE);
  short* vT_ws = (short*)(ws + 16 * MBYTE);

  dim3 ggrid(D_MODELX / 128, M_TOK / 128);

  if (ws_size >= (size_t)56 * MBYTE) {
    short* wq_bf = (short*)(ws + 24 * MBYTE);
    short* wk_bf = (short*)(ws + 26 * MBYTE);
    short* wv_bf = (short*)(ws + 28 * MBYTE);
    short* wo_bf = (short*)(ws + 30 * MBYTE);
    short* xq_bf = (short*)(ws + 32 * MBYTE);
    short* xk_bf = (short*)(ws + 40 * MBYTE);
    short* xv_bf = (short*)(ws + 48 * MBYTE);
    short* attn_ws = (short*)(ws + 32 * MBYTE);          // aliases xq_bf (dead after qkv gemm)
    unsigned* mbits = (unsigned*)(ws + 40 * MBYTE);      // aliases xk_bf (dead after qkv gemm)

    cvt_w4_kernel<<<dim3(1024, 4), 256, 0, stream>>>(Wq, Wk, Wv, Wo, wq_bf, wk_bf, wv_bf, wo_bf);
    cvt_x3_kernel<<<dim3(4096, 3), 256, 0, stream>>>(x_q, x_k, x_v, xq_bf, xk_bf, xv_bf);

    dim3 qkvgrid(D_MODELX / 128, M_TOK / 128, 3);
    gemm_qkv_kernel<<<qkvgrid, 256, 0, stream>>>(xq_bf, xk_bf, xv_bf, wq_bf, wk_bf, wv_bf,
                                                 bq, bk, bv, q_ws, k_ws, vT_ws, QSCALE);

    mask_bits_kernel<<<(BBX * SSX * SSX) / 256, 256, 0, stream>>>(mask, mbits);

    attn_kernel<<<BBX * NUM_HEADX * (SSX / 64), 256, 0, stream>>>(q_ws, k_ws, vT_ws, mbits, attn_ws);

    gemm_one_kernel<<<ggrid, 256, 0, stream>>>(attn_ws, wo_bf, bo, 1.0f, d_out, 1);
  } else {
    // sequential low-footprint path (35 MB)
    unsigned* mbits = (unsigned*)(ws + 24 * MBYTE);
    short* w_bf = (short*)(ws + 25 * MBYTE);
    short* x_bf = (short*)(ws + 27 * MBYTE);
    short* attn_ws = (short*)(ws + 27 * MBYTE);  // aliases x_bf

    mask_bits_kernel<<<(BBX * SSX * SSX) / 256, 256, 0, stream>>>(mask, mbits);

    cvt_w4_kernel<<<dim3(1024, 1), 256, 0, stream>>>(Wq, Wq, Wq, Wq, w_bf, w_bf, w_bf, w_bf);
    cvt_x3_kernel<<<dim3(4096, 1), 256, 0, stream>>>(x_q, x_q, x_q, x_bf, x_bf, x_bf);
    gemm_one_kernel<<<ggrid, 256, 0, stream>>>(x_bf, w_bf, bq, QSCALE, q_ws, 0);

    cvt_w4_kernel<<<dim3(1024, 1), 256, 0, stream>>>(Wk, Wk, Wk, Wk, w_bf, w_bf, w_bf, w_bf);
    cvt_x3_kernel<<<dim3(4096, 1), 256, 0, stream>>>(x_k, x_k, x_k, x_bf, x_bf, x_bf);
    gemm_one_kernel<<<ggrid, 256, 0, stream>>>(x_bf, w_bf, bk, 1.0f, k_ws, 0);

    cvt_w4_kernel<<<dim3(1024, 1), 256, 0, stream>>>(Wv, Wv, Wv, Wv, w_bf, w_bf, w_bf, w_bf);
    cvt_x3_kernel<<<dim3(4096, 1), 256, 0, stream>>>(x_v, x_v, x_v, x_bf, x_bf, x_bf);
    gemm_one_kernel<<<ggrid, 256, 0, stream>>>(x_bf, w_bf, bv, 1.0f, vT_ws, 2);

    attn_kernel<<<BBX * NUM_HEADX * (SSX / 64), 256, 0, stream>>>(q_ws, k_ws, vT_ws, mbits, attn_ws);

    cvt_w4_kernel<<<dim3(1024, 1), 256, 0, stream>>>(Wo, Wo, Wo, Wo, w_bf, w_bf, w_bf, w_bf);
    gemm_one_kernel<<<ggrid, 256, 0, stream>>>(attn_ws, w_bf, bo, 1.0f, d_out, 1);
  }
}